// Round 10
// baseline (305.846 us; speedup 1.0000x reference)
//
#include <hip/hip_runtime.h>
#include <math.h>

#define N_NODES 10000
#define N_EDGES 320000
#define TILES 5                 // edge_mlp: 5 tiles x 32 edges per block
#define NBLK (N_EDGES / (32 * TILES))   // 2000 blocks

#define SQRT3F     1.7320508075688772f
#define INV_SQRT3F 0.5773502691896258f
#define INV_SQRT2F 0.7071067811865476f

typedef short bf16x8 __attribute__((ext_vector_type(8)));
typedef short b16x4  __attribute__((ext_vector_type(4)));
typedef float f32x4  __attribute__((ext_vector_type(4)));
typedef unsigned int u32;

static __device__ __forceinline__ unsigned short f2b(float f) {
    unsigned int u = __float_as_uint(f);
    unsigned int r = (u + 0x7fffu + ((u >> 16) & 1u)) >> 16;   // RNE
    return (unsigned short)r;
}
static __device__ __forceinline__ float b2f(unsigned short h) {
    return __uint_as_float(((unsigned int)h) << 16);
}

// direct global->LDS 16B copy (lane-linear dest: base + lane*16)
static __device__ __forceinline__ void gl_lds16(const void* g, void* l) {
    __builtin_amdgcn_global_load_lds(
        (const __attribute__((address_space(1))) u32*)g,
        (__attribute__((address_space(3))) u32*)l,
        16, 0, 0);
}

// ---------------------------------------------------------------------------
// Kernel P: merged prep — node transforms (blocks 0..6249), src histogram
// (6250..7499), weight conversion (7500..7571).
//   st_vt16[n][160] bf16: [0..63] s_t = nf_s @ W_nl0
//                         [64..159] v_t TRANSPOSED layout i*32+k
// ---------------------------------------------------------------------------
__global__ __launch_bounds__(256) void prep_kernel(
    const float* __restrict__ nf,
    const float* __restrict__ Wnl0,
    const float* __restrict__ Wnl1,
    const float* __restrict__ Wfc1,
    const float* __restrict__ Wfc2,
    const int* __restrict__ eidx,
    unsigned short* __restrict__ st_vt16,
    unsigned short* __restrict__ W1T,
    unsigned short* __restrict__ W2T,
    int* __restrict__ cnt)
{
    const int b = blockIdx.x;
    const int tid = threadIdx.x;
    if (b < 6250) {
        int gid = b * 256 + tid;
        if (gid >= N_NODES * 160) return;
        int n = gid / 160;
        int j = gid - n * 160;
        const float* nfn = nf + (size_t)n * 160;
        float acc = 0.f;
        if (j < 64) {
            #pragma unroll 8
            for (int k = 0; k < 64; ++k) acc += nfn[k] * Wnl0[k * 64 + j];
        } else {
            int t = j - 64;
            int i = t >> 5, k = t & 31;
            #pragma unroll 8
            for (int m = 0; m < 32; ++m) acc += nfn[64 + m * 3 + i] * Wnl1[m * 32 + k];
        }
        st_vt16[(size_t)n * 160 + j] = f2b(acc);
    } else if (b < 7500) {
        int e = (b - 6250) * 256 + tid;
        if (e < N_EDGES) atomicAdd(&cnt[eidx[e]], 1);
    } else {
        int idx = (b - 7500) * 256 + tid;
        if (idx < 4096) {
            int n = idx >> 6, k = idx & 63;
            W1T[idx] = f2b(Wfc1[k * 64 + n]);
        } else if (idx < 18432) {
            int j = idx - 4096;
            int n = j >> 6, k = j & 63;
            W2T[j] = f2b(Wfc2[k * 224 + n]);
        }
    }
}

// ---------------------------------------------------------------------------
// scan + scatter (sorting by src)
// ---------------------------------------------------------------------------
__global__ __launch_bounds__(1024) void scan_kernel(
    const int* __restrict__ cnt, int* __restrict__ row_start)
{
    __shared__ int part[1024];
    const int t = threadIdx.x;
    const int CH = 10;
    int base = t * CH;
    int s = 0;
    for (int i = 0; i < CH; ++i) {
        int idx = base + i;
        if (idx < N_NODES) s += cnt[idx];
    }
    part[t] = s;
    __syncthreads();
    for (int off = 1; off < 1024; off <<= 1) {
        int v = (t >= off) ? part[t - off] : 0;
        __syncthreads();
        part[t] += v;
        __syncthreads();
    }
    int run = (t == 0) ? 0 : part[t - 1];
    for (int i = 0; i < CH; ++i) {
        int idx = base + i;
        if (idx < N_NODES) { row_start[idx] = run; run += cnt[idx]; }
    }
    if (t == 1023) row_start[N_NODES] = run;
}

__global__ __launch_bounds__(256) void scatter_kernel(
    const int* __restrict__ eidx, const float* __restrict__ edge_attr,
    const int* __restrict__ row_start,
    int* __restrict__ fill, int* __restrict__ order,
    int* __restrict__ src_srt, int* __restrict__ dst_srt,
    float* __restrict__ sh_srt)
{
    int e = blockIdx.x * 256 + threadIdx.x;
    if (e >= N_EDGES) return;
    int s = eidx[e];
    int p = atomicAdd(&fill[s], 1) + row_start[s];
    order[p] = e;
    src_srt[p] = s;
    dst_srt[p] = eidx[N_EDGES + e];
    float x = edge_attr[(size_t)e * 3 + 0];
    float y = edge_attr[(size_t)e * 3 + 1];
    float z = edge_attr[(size_t)e * 3 + 2];
    float inv = SQRT3F / sqrtf(x * x + y * y + z * z);
    sh_srt[(size_t)p * 4 + 0] = x * inv;
    sh_srt[(size_t)p * 4 + 1] = y * inv;
    sh_srt[(size_t)p * 4 + 2] = z * inv;
    sh_srt[(size_t)p * 4 + 3] = 0.f;
}

// ---------------------------------------------------------------------------
// Kernel A: pure MFMA MLP pipeline. Writes w_srt[p][224] bf16 coalesced.
// ---------------------------------------------------------------------------
__global__ __launch_bounds__(256, 5) void edge_mlp(
    const unsigned short* __restrict__ W1T,
    const unsigned short* __restrict__ W2T,
    const int* __restrict__ order,
    const float* __restrict__ edge_feature,
    unsigned short* __restrict__ w_srt)
{
    __shared__ __align__(16) unsigned short A1[32 * 64];      // 4 KB (swizzled)
    __shared__ __align__(16) unsigned short Hs[32 * 64];      // 4 KB (swizzled)
    __shared__ __align__(16) unsigned short w_s[32 * 224];    // 14 KB
    __shared__ int eid_s[160];

    const int tid  = threadIdx.x;
    const int lane = tid & 63;
    const int wv   = tid >> 6;
    const int l15  = lane & 15;
    const int g    = lane >> 4;
    const int p0   = blockIdx.x * (32 * TILES);

    bf16x8 w1b0 = *reinterpret_cast<const bf16x8*>(&W1T[(wv * 16 + l15) * 64 + g * 8]);
    bf16x8 w1b1 = *reinterpret_cast<const bf16x8*>(&W1T[(wv * 16 + l15) * 64 + 32 + g * 8]);
    bf16x8 w2b0[4], w2b1[4];
    #pragma unroll
    for (int ii = 0; ii < 4; ++ii) {
        int nt = wv * 4 + ii;
        w2b0[ii] = *reinterpret_cast<const bf16x8*>(&W2T[(nt * 16 + l15) * 64 + g * 8]);
        w2b1[ii] = *reinterpret_cast<const bf16x8*>(&W2T[(nt * 16 + l15) * 64 + 32 + g * 8]);
    }

    if (tid < 32 * TILES) eid_s[tid] = order[p0 + tid];
    __syncthreads();

    f32x4 efr[2];
    auto load_ef = [&](int t) {
        int ebase = t * 32;
        #pragma unroll
        for (int r = 0; r < 2; ++r) {
            int q = tid + r * 256;
            int el = q >> 4, qf = q & 15;
            efr[r] = *reinterpret_cast<const f32x4*>(
                edge_feature + (size_t)eid_s[ebase + el] * 64 + qf * 4);
        }
    };
    auto write_ef = [&]() {
        #pragma unroll
        for (int r = 0; r < 2; ++r) {
            int q = tid + r * 256;
            int el = q >> 4, f0 = (q & 15) * 4;
            b16x4 h;
            #pragma unroll
            for (int j = 0; j < 4; ++j) h[j] = (short)f2b(efr[r][j]);
            *reinterpret_cast<b16x4*>(&A1[el * 64 + (f0 ^ ((el & 7) << 3))]) = h;
        }
    };

    load_ef(0);

    for (int t = 0; t < TILES; ++t) {
        write_ef();
        __syncthreads();
        if (t < TILES - 1) load_ef(t + 1);

        // GEMM1: Hs = relu(A1 @ Wfc1)
        {
            const int nt = wv;
            #pragma unroll
            for (int mt = 0; mt < 2; ++mt) {
                f32x4 c4 = {0.f, 0.f, 0.f, 0.f};
                int ra = mt * 16 + l15;
                int sw = (ra & 7) << 3;
                bf16x8 a0 = *reinterpret_cast<const bf16x8*>(&A1[ra * 64 + ((g * 8) ^ sw)]);
                bf16x8 a1 = *reinterpret_cast<const bf16x8*>(&A1[ra * 64 + ((32 + g * 8) ^ sw)]);
                c4 = __builtin_amdgcn_mfma_f32_16x16x32_bf16(a0, w1b0, c4, 0, 0, 0);
                c4 = __builtin_amdgcn_mfma_f32_16x16x32_bf16(a1, w1b1, c4, 0, 0, 0);
                #pragma unroll
                for (int r = 0; r < 4; ++r) {
                    int row = mt * 16 + g * 4 + r;
                    int col = nt * 16 + l15;
                    Hs[row * 64 + (col ^ ((row & 7) << 3))] = f2b(fmaxf(c4[r], 0.f));
                }
            }
        }
        __syncthreads();

        // GEMM2: w_s = Hs @ Wfc2 (stores masked nt<14)
        {
            #pragma unroll
            for (int ii = 0; ii < 4; ++ii) {
                int nt = wv * 4 + ii;
                #pragma unroll
                for (int mt = 0; mt < 2; ++mt) {
                    f32x4 c4 = {0.f, 0.f, 0.f, 0.f};
                    int ra = mt * 16 + l15;
                    int sw = (ra & 7) << 3;
                    bf16x8 a0 = *reinterpret_cast<const bf16x8*>(&Hs[ra * 64 + ((g * 8) ^ sw)]);
                    bf16x8 a1 = *reinterpret_cast<const bf16x8*>(&Hs[ra * 64 + ((32 + g * 8) ^ sw)]);
                    c4 = __builtin_amdgcn_mfma_f32_16x16x32_bf16(a0, w2b0[ii], c4, 0, 0, 0);
                    c4 = __builtin_amdgcn_mfma_f32_16x16x32_bf16(a1, w2b1[ii], c4, 0, 0, 0);
                    if (nt < 14) {
                        #pragma unroll
                        for (int r = 0; r < 4; ++r) {
                            int row = mt * 16 + g * 4 + r;
                            w_s[row * 224 + nt * 16 + l15] = f2b(c4[r]);
                        }
                    }
                }
            }
        }
        __syncthreads();

        // coalesced copy-out: 32x224 u16 = 896 x 16B
        {
            const size_t gbase = (size_t)(p0 + t * 32) * 224;
            for (int idx = tid; idx < 896; idx += 256) {
                *reinterpret_cast<f32x4*>(&w_srt[gbase + idx * 8]) =
                    *reinterpret_cast<const f32x4*>(&w_s[idx * 8]);
            }
        }
    }
}

// ---------------------------------------------------------------------------
// Kernel B: per-NODE messages, v2. One block per node; edges contiguous.
// Zero atomics. w read DIRECTLY from global (sequential rows, stream-once);
// df staged via global_load_lds (dst inline, clamped). LDS ~13 KB -> 8 blk/CU.
// ---------------------------------------------------------------------------
__global__ __launch_bounds__(256, 8) void node_msg(
    const int* __restrict__ row_start,
    const int* __restrict__ dst_srt,
    const float* __restrict__ sh_srt,
    const unsigned short* __restrict__ w_srt,
    const unsigned short* __restrict__ st_vt16,
    const float* __restrict__ nf,
    const float* __restrict__ Wskip0,
    const float* __restrict__ Wskip1,
    const float* __restrict__ Wout_s,
    const float* __restrict__ Wout_v,
    float* __restrict__ out)
{
    __shared__ __align__(16) unsigned short df[32 * 160];   // 10240 B
    __shared__ float aggbuf[480];
    __shared__ float os_s[96];
    __shared__ float sh_c[32][4];

    // chunked XCD remap (10000 = 8 * 1250)
    const int n   = (blockIdx.x & 7) * 1250 + (blockIdx.x >> 3);
    const int tid = threadIdx.x;
    const int p_start = row_start[n];
    const int p_end   = row_start[n + 1];

    // region setup (fixed per thread); halves tid<128 / tid>=128 split edges
    const int tid2 = tid & 127;
    const int half = tid >> 7;
    int region, cb, iv;
    if (tid2 < 48)       { region = 0; cb = tid2 & 15;        iv = tid2 >> 4; }
    else if (tid2 < 64)  { region = 1; cb = tid2 - 48;        iv = 0; }
    else if (tid2 < 88)  { region = 2; cb = (tid2 - 64) & 7;  iv = (tid2 - 64) >> 3; }
    else if (tid2 < 112) { region = 3; cb = (tid2 - 88) & 7;  iv = (tid2 - 88) >> 3; }
    else if (tid2 < 120) { region = 4; cb = tid2 - 112;       iv = 0; }
    else                 { region = 5; cb = 0; iv = 0; }
    int rbase = 0, woff = 0, doff = 0;
    if (region == 0)      { rbase = 96 + iv * 64 + 4 * cb;  woff = 64 + 4 * cb;  doff = 4 * cb; }
    else if (region == 1) { rbase = 4 * cb;                 woff = 4 * cb;       doff = 4 * cb; }
    else if (region == 2) { rbase = 288 + iv * 32 + 4 * cb; woff = 128 + 4 * cb; doff = 64 + iv * 32 + 4 * cb; }
    else if (region == 3) { rbase = 384 + iv * 32 + 4 * cb; woff = 192 + 4 * cb; }
    else if (region == 4) { rbase = 64 + 4 * cb;            woff = 160 + 4 * cb; }
    int i1 = iv + 1; if (i1 == 3) i1 = 0;
    int i2 = 3 - iv - i1;

    f32x4 acc = {0.f, 0.f, 0.f, 0.f};

    for (int pb = p_start; pb < p_end; pb += 32) {
        __syncthreads();                       // df/sh_c reuse guard

        // stage sh for this chunk
        if (tid < 32) {
            int pp = min(pb + tid, p_end - 1);
            *reinterpret_cast<f32x4*>(&sh_c[tid][0]) =
                *reinterpret_cast<const f32x4*>(&sh_srt[(size_t)pp * 4]);
        }
        // issue df gathers (dst read inline, clamped)
        #pragma unroll
        for (int r = 0; r < 3; ++r) {
            int idx = tid + r * 256;
            if (idx < 640) {                   // wave-uniform on/off
                int el = idx / 20, off = idx - el * 20;
                int pp = min(pb + el, p_end - 1);
                int d = dst_srt[pp];
                gl_lds16(st_vt16 + (size_t)d * 160 + off * 8, &df[idx * 8]);
            }
        }
        __syncthreads();                       // vmcnt drained: df + sh_c ready

        const int nvalid = p_end - pb;
        if (region < 5) {
            const int e0l = half * 16;
            #pragma unroll 4
            for (int j2 = 0; j2 < 16; ++j2) {
                int el = e0l + j2;
                if (el >= nvalid) break;       // uniform per half
                const unsigned short* dfp = &df[el * 160];
                const unsigned short* we  = w_srt + (size_t)(pb + el) * 224;  // GLOBAL
                b16x4 w = *reinterpret_cast<const b16x4*>(we + woff);
                if (region == 0) {
                    b16x4 x = *reinterpret_cast<const b16x4*>(dfp + doff);
                    float sh = sh_c[el][iv];
                    #pragma unroll
                    for (int j = 0; j < 4; ++j)
                        acc[j] += b2f((unsigned short)w[j]) * b2f((unsigned short)x[j]) * sh;
                } else if (region == 1 || region == 2) {
                    b16x4 x = *reinterpret_cast<const b16x4*>(dfp + doff);
                    #pragma unroll
                    for (int j = 0; j < 4; ++j)
                        acc[j] += b2f((unsigned short)w[j]) * b2f((unsigned short)x[j]);
                } else if (region == 3) {
                    b16x4 xA = *reinterpret_cast<const b16x4*>(dfp + 64 + i1 * 32 + 4 * cb);
                    b16x4 xB = *reinterpret_cast<const b16x4*>(dfp + 64 + i2 * 32 + 4 * cb);
                    float shA = sh_c[el][i1], shB = sh_c[el][i2];
                    #pragma unroll
                    for (int j = 0; j < 4; ++j)
                        acc[j] += b2f((unsigned short)w[j]) *
                                  (b2f((unsigned short)xA[j]) * shB -
                                   b2f((unsigned short)xB[j]) * shA) * INV_SQRT2F;
                } else {
                    b16x4 x0 = *reinterpret_cast<const b16x4*>(dfp + 64 + 4 * cb);
                    b16x4 x1 = *reinterpret_cast<const b16x4*>(dfp + 96 + 4 * cb);
                    b16x4 x2 = *reinterpret_cast<const b16x4*>(dfp + 128 + 4 * cb);
                    float s0 = sh_c[el][0], s1 = sh_c[el][1], s2 = sh_c[el][2];
                    #pragma unroll
                    for (int j = 0; j < 4; ++j)
                        acc[j] += b2f((unsigned short)w[j]) *
                                  (b2f((unsigned short)x0[j]) * s0 +
                                   b2f((unsigned short)x1[j]) * s1 +
                                   b2f((unsigned short)x2[j]) * s2) * INV_SQRT3F;
                }
            }
        }
    }

    // combine halves into aggbuf
    __syncthreads();
    if (half == 0 && region < 5) {
        #pragma unroll
        for (int j = 0; j < 4; ++j) aggbuf[rbase + j] = acc[j];
    }
    __syncthreads();
    if (half == 1 && region < 5) {
        #pragma unroll
        for (int j = 0; j < 4; ++j) aggbuf[rbase + j] += acc[j];
    }
    __syncthreads();

    // fused output transform + gating
    const float* nfn = nf + (size_t)n * 160;
    if (tid < 96) {
        float sk = 0.f;
        #pragma unroll 8
        for (int k = 0; k < 64; ++k) sk += nfn[k] * Wskip0[k * 96 + tid];
        float a = 0.f;
        for (int r = 0; r < 96; ++r) a += aggbuf[r] * Wout_s[r * 96 + tid];
        os_s[tid] = a * (1.f / 32.f) + sk;
    }
    __syncthreads();

    if (tid < 64) {
        float x = os_s[tid];
        out[(size_t)n * 160 + tid] = x / (1.f + expf(-x));  // silu
    }
    if (tid < 96) {
        int t = tid;
        int k = t / 3, i = t - 3 * k;
        float sk = 0.f;
        #pragma unroll 8
        for (int m = 0; m < 32; ++m) sk += nfn[64 + m * 3 + i] * Wskip1[m * 32 + k];
        float a = 0.f;
        #pragma unroll 8
        for (int m = 0; m < 64; ++m) a += aggbuf[96 + i * 64 + m] * Wout_v[m * 32 + k];
        #pragma unroll 8
        for (int m = 0; m < 32; ++m) a += aggbuf[288 + i * 32 + m] * Wout_v[(64 + m) * 32 + k];
        #pragma unroll 8
        for (int m = 0; m < 32; ++m) a += aggbuf[384 + i * 32 + m] * Wout_v[(96 + m) * 32 + k];
        float g = os_s[64 + k];
        g = 1.f / (1.f + expf(-g));  // sigmoid gate
        out[(size_t)n * 160 + 64 + t] = g * (a * (1.f / 32.f) + sk);
    }
}

// ---------------------------------------------------------------------------
// Fallback path (only if ws can't hold w_srt): round-6 fused kernel + out.
// ---------------------------------------------------------------------------
__global__ __launch_bounds__(256, 3) void edge_conv_fused(
    const unsigned short* __restrict__ W1T,
    const unsigned short* __restrict__ W2T,
    const int* __restrict__ order,
    const int* __restrict__ src_srt,
    const int* __restrict__ dst_srt,
    const float* __restrict__ sh_srt,
    const float* __restrict__ edge_feature,
    const unsigned short* __restrict__ st_vt16,
    float* __restrict__ agg)
{
    __shared__ __align__(16) unsigned short A1[32 * 64];
    __shared__ __align__(16) unsigned short Hs[32 * 64];
    __shared__ __align__(16) unsigned short w_s[32 * 224];
    __shared__ __align__(16) unsigned short df[2][32 * 160];
    __shared__ int   eid_s[160];
    __shared__ int   src_s[160];
    __shared__ int   dst_s[160];
    __shared__ float sh_s[160][4];

    const int tid  = threadIdx.x;
    const int lane = tid & 63;
    const int wv   = tid >> 6;
    const int l15  = lane & 15;
    const int g    = lane >> 4;
    const int p0   = blockIdx.x * (32 * TILES);

    bf16x8 w1b0 = *reinterpret_cast<const bf16x8*>(&W1T[(wv * 16 + l15) * 64 + g * 8]);
    bf16x8 w1b1 = *reinterpret_cast<const bf16x8*>(&W1T[(wv * 16 + l15) * 64 + 32 + g * 8]);
    bf16x8 w2b0[4], w2b1[4];
    #pragma unroll
    for (int ii = 0; ii < 4; ++ii) {
        int nt = wv * 4 + ii;
        w2b0[ii] = *reinterpret_cast<const bf16x8*>(&W2T[(nt * 16 + l15) * 64 + g * 8]);
        w2b1[ii] = *reinterpret_cast<const bf16x8*>(&W2T[(nt * 16 + l15) * 64 + 32 + g * 8]);
    }

    if (tid < 32 * TILES) {
        int p = p0 + tid;
        eid_s[tid] = order[p];
        src_s[tid] = src_srt[p];
        dst_s[tid] = dst_srt[p];
        *reinterpret_cast<f32x4*>(&sh_s[tid][0]) =
            *reinterpret_cast<const f32x4*>(&sh_srt[(size_t)p * 4]);
    }
    __syncthreads();

    const int tid2 = tid & 127;
    int region, cb, iv;
    if (tid2 < 48)       { region = 0; cb = tid2 & 15;        iv = tid2 >> 4; }
    else if (tid2 < 64)  { region = 1; cb = tid2 - 48;        iv = 0; }
    else if (tid2 < 88)  { region = 2; cb = (tid2 - 64) & 7;  iv = (tid2 - 64) >> 3; }
    else if (tid2 < 112) { region = 3; cb = (tid2 - 88) & 7;  iv = (tid2 - 88) >> 3; }
    else if (tid2 < 120) { region = 4; cb = tid2 - 112;       iv = 0; }
    else                 { region = 5; cb = 0; iv = 0; }
    int rbase = 0, woff = 0, doff = 0;
    if (region == 0)      { rbase = 96 + iv * 64 + 4 * cb;  woff = 64 + 4 * cb;  doff = 4 * cb; }
    else if (region == 1) { rbase = 4 * cb;                 woff = 4 * cb;       doff = 4 * cb; }
    else if (region == 2) { rbase = 288 + iv * 32 + 4 * cb; woff = 128 + 4 * cb; doff = 64 + iv * 32 + 4 * cb; }
    else if (region == 3) { rbase = 384 + iv * 32 + 4 * cb; woff = 192 + 4 * cb; }
    else if (region == 4) { rbase = 64 + 4 * cb;            woff = 160 + 4 * cb; }
    int i1 = iv + 1; if (i1 == 3) i1 = 0;
    int i2 = 3 - iv - i1;

    f32x4 acc = {0.f, 0.f, 0.f, 0.f};
    int cur = src_s[(tid >> 7) * 16];

    f32x4 efr[2];
    auto load_ef = [&](int t) {
        int ebase = t * 32;
        #pragma unroll
        for (int r = 0; r < 2; ++r) {
            int q = tid + r * 256;
            int el = q >> 4, qf = q & 15;
            efr[r] = *reinterpret_cast<const f32x4*>(
                edge_feature + (size_t)eid_s[ebase + el] * 64 + qf * 4);
        }
    };
    auto write_ef = [&]() {
        #pragma unroll
        for (int r = 0; r < 2; ++r) {
            int q = tid + r * 256;
            int el = q >> 4, f0 = (q & 15) * 4;
            b16x4 h;
            #pragma unroll
            for (int j = 0; j < 4; ++j) h[j] = (short)f2b(efr[r][j]);
            *reinterpret_cast<b16x4*>(&A1[el * 64 + (f0 ^ ((el & 7) << 3))]) = h;
        }
    };
    auto issue_df = [&](int t, int b) {
        int ebase = t * 32;
        #pragma unroll
        for (int r = 0; r < 3; ++r) {
            int idx = tid + r * 256;
            if (idx < 640) {
                int el = idx / 20, off = idx - el * 20;
                gl_lds16(st_vt16 + (size_t)dst_s[ebase + el] * 160 + off * 8,
                         &df[b][idx * 8]);
            }
        }
    };

    issue_df(0, 0);
    load_ef(0);

    for (int t = 0; t < TILES; ++t) {
        const int b = t & 1;
        write_ef();
        __syncthreads();
        if (t < TILES - 1) {
            issue_df(t + 1, b ^ 1);
            load_ef(t + 1);
        }
        {
            const int nt = wv;
            #pragma unroll
            for (int mt = 0; mt < 2; ++mt) {
                f32x4 c4 = {0.f, 0.f, 0.f, 0.f};
                int ra = mt * 16 + l15;
                int sw = (ra & 7) << 3;
                bf16x8 a0 = *reinterpret_cast<const bf16x8*>(&A1[ra * 64 + ((g * 8) ^ sw)]);
                bf16x8 a1 = *reinterpret_cast<const bf16x8*>(&A1[ra * 64 + ((32 + g * 8) ^ sw)]);
                c4 = __builtin_amdgcn_mfma_f32_16x16x32_bf16(a0, w1b0, c4, 0, 0, 0);
                c4 = __builtin_amdgcn_mfma_f32_16x16x32_bf16(a1, w1b1, c4, 0, 0, 0);
                #pragma unroll
                for (int r = 0; r < 4; ++r) {
                    int row = mt * 16 + g * 4 + r;
                    int col = nt * 16 + l15;
                    Hs[row * 64 + (col ^ ((row & 7) << 3))] = f2b(fmaxf(c4[r], 0.f));
                }
            }
        }
        __syncthreads();
        {
            #pragma unroll
            for (int ii = 0; ii < 4; ++ii) {
                int nt = wv * 4 + ii;
                #pragma unroll
                for (int mt = 0; mt < 2; ++mt) {
                    f32x4 c4 = {0.f, 0.f, 0.f, 0.f};
                    int ra = mt * 16 + l15;
                    int sw = (ra & 7) << 3;
                    bf16x8 a0 = *reinterpret_cast<const bf16x8*>(&Hs[ra * 64 + ((g * 8) ^ sw)]);
                    bf16x8 a1 = *reinterpret_cast<const bf16x8*>(&Hs[ra * 64 + ((32 + g * 8) ^ sw)]);
                    c4 = __builtin_amdgcn_mfma_f32_16x16x32_bf16(a0, w2b0[ii], c4, 0, 0, 0);
                    c4 = __builtin_amdgcn_mfma_f32_16x16x32_bf16(a1, w2b1[ii], c4, 0, 0, 0);
                    if (nt < 14) {
                        #pragma unroll
                        for (int r = 0; r < 4; ++r) {
                            int row = mt * 16 + g * 4 + r;
                            w_s[row * 224 + nt * 16 + l15] = f2b(c4[r]);
                        }
                    }
                }
            }
        }
        __syncthreads();
        if (region < 5) {
            const int e0l = (tid >> 7) * 16;
            #pragma unroll 4
            for (int j2 = 0; j2 < 16; ++j2) {
                int el = e0l + j2;
                int eg = t * 32 + el;
                int s = src_s[eg];
                if (s != cur) {
                    #pragma unroll
                    for (int j = 0; j < 4; ++j)
                        atomicAdd(&agg[(size_t)cur * 480 + rbase + j], acc[j]);
                    acc = (f32x4){0.f, 0.f, 0.f, 0.f};
                    cur = s;
                }
                const unsigned short* dfp = &df[b][el * 160];
                const unsigned short* we  = &w_s[el * 224];
                b16x4 w = *reinterpret_cast<const b16x4*>(we + woff);
                if (region == 0) {
                    b16x4 x = *reinterpret_cast<const b16x4*>(dfp + doff);
                    float sh = sh_s[eg][iv];
                    #pragma unroll
                    for (int j = 0; j < 4; ++j)
                        acc[j] += b2f((unsigned short)w[j]) * b2f((unsigned short)x[j]) * sh;
                } else if (region == 1 || region == 2) {
                    b16x4 x = *reinterpret_cast<const b16x4*>(dfp + doff);
                    #pragma unroll
                    for (int j = 0; j < 4; ++j)
                        acc[j] += b2f((unsigned short)w[j]) * b2f((unsigned short)x[j]);
                } else if (region == 3) {
                    b16x4 xA = *reinterpret_cast<const b16x4*>(dfp + 64 + i1 * 32 + 4 * cb);
                    b16x4 xB = *reinterpret_cast<const b16x4*>(dfp + 64 + i2 * 32 + 4 * cb);
                    float shA = sh_s[eg][i1], shB = sh_s[eg][i2];
                    #pragma unroll
                    for (int j = 0; j < 4; ++j)
                        acc[j] += b2f((unsigned short)w[j]) *
                                  (b2f((unsigned short)xA[j]) * shB -
                                   b2f((unsigned short)xB[j]) * shA) * INV_SQRT2F;
                } else {
                    b16x4 x0 = *reinterpret_cast<const b16x4*>(dfp + 64 + 4 * cb);
                    b16x4 x1 = *reinterpret_cast<const b16x4*>(dfp + 96 + 4 * cb);
                    b16x4 x2 = *reinterpret_cast<const b16x4*>(dfp + 128 + 4 * cb);
                    float s0 = sh_s[eg][0], s1 = sh_s[eg][1], s2 = sh_s[eg][2];
                    #pragma unroll
                    for (int j = 0; j < 4; ++j)
                        acc[j] += b2f((unsigned short)w[j]) *
                                  (b2f((unsigned short)x0[j]) * s0 +
                                   b2f((unsigned short)x1[j]) * s1 +
                                   b2f((unsigned short)x2[j]) * s2) * INV_SQRT3F;
                }
            }
        }
    }
    if (region < 5) {
        #pragma unroll
        for (int j = 0; j < 4; ++j)
            atomicAdd(&agg[(size_t)cur * 480 + rbase + j], acc[j]);
    }
}

__global__ __launch_bounds__(128) void out_kernel(
    const float* __restrict__ agg,
    const float* __restrict__ nf,
    const float* __restrict__ Wskip0,
    const float* __restrict__ Wskip1,
    const float* __restrict__ Wout_s,
    const float* __restrict__ Wout_v,
    float* __restrict__ out)
{
    __shared__ float aggl[480];
    __shared__ float os_s[96];
    const int n = blockIdx.x;
    const int tid = threadIdx.x;
    const float* nfn = nf + (size_t)n * 160;

    for (int idx = tid; idx < 480; idx += 128)
        aggl[idx] = agg[(size_t)n * 480 + idx] * (1.f / 32.f);
    __syncthreads();

    if (tid < 96) {
        float acc = 0.f;
        #pragma unroll 8
        for (int k = 0; k < 64; ++k) acc += nfn[k] * Wskip0[k * 96 + tid];
        for (int r = 0; r < 96; ++r) acc += aggl[r] * Wout_s[r * 96 + tid];
        os_s[tid] = acc;
    }
    __syncthreads();

    if (tid < 64) {
        float x = os_s[tid];
        out[(size_t)n * 160 + tid] = x / (1.f + expf(-x));
    }
    if (tid < 96) {
        int t = tid;
        int k = t / 3, i = t - 3 * k;
        float acc = 0.f;
        #pragma unroll 8
        for (int m = 0; m < 32; ++m) acc += nfn[64 + m * 3 + i] * Wskip1[m * 32 + k];
        #pragma unroll 8
        for (int m = 0; m < 64; ++m) acc += aggl[96 + i * 64 + m] * Wout_v[m * 32 + k];
        #pragma unroll 8
        for (int m = 0; m < 32; ++m) acc += aggl[288 + i * 32 + m] * Wout_v[(64 + m) * 32 + k];
        #pragma unroll 8
        for (int m = 0; m < 32; ++m) acc += aggl[384 + i * 32 + m] * Wout_v[(96 + m) * 32 + k];
        float g = os_s[64 + k];
        g = 1.f / (1.f + expf(-g));
        out[(size_t)n * 160 + 64 + t] = g * acc;
    }
}

// ---------------------------------------------------------------------------
extern "C" void kernel_launch(void* const* d_in, const int* in_sizes, int n_in,
                              void* d_out, int out_size, void* d_ws, size_t ws_size,
                              hipStream_t stream)
{
    const float* nf     = (const float*)d_in[0];
    const float* ea     = (const float*)d_in[1];
    const float* ef     = (const float*)d_in[2];
    const float* Wskip0 = (const float*)d_in[3];
    const float* Wskip1 = (const float*)d_in[4];
    const float* Wnl0   = (const float*)d_in[5];
    const float* Wnl1   = (const float*)d_in[6];
    const float* Wfc1   = (const float*)d_in[7];
    const float* Wfc2   = (const float*)d_in[8];
    const float* Wout_s = (const float*)d_in[9];
    const float* Wout_v = (const float*)d_in[10];
    const int*   eidx   = (const int*)d_in[11];
    float* out = (float*)d_out;

    // workspace layout (16B-aligned sections)
    int*   cnt       = (int*)d_ws;                        // 10000
    int*   fill      = cnt + 10000;                       // 10000
    int*   row_start = fill + 10000;                      // 10004
    int*   order     = row_start + 10004;                 // 320000
    int*   src_srt   = order + 320000;                    // 320000
    int*   dst_srt   = src_srt + 320000;                  // 320000
    float* sh_srt    = (float*)(dst_srt + 320000);        // 1,280,000
    float* agg       = sh_srt + 1280000;                  // 4,800,000 (fallback only)
    unsigned short* st_vt16 = (unsigned short*)(agg + 4800000); // 1,600,000
    unsigned short* W1T = st_vt16 + 1600000;              // 4,096
    unsigned short* W2T = W1T + 4096;                     // 16,384 (256 rows, 224 valid)
    unsigned short* w_srt = W2T + 16384;                  // (N_EDGES+32)*224 (split only)

    const size_t need_split =
        (size_t)((const char*)(w_srt + (size_t)(N_EDGES + 32) * 224) - (const char*)d_ws);
    const bool use_split = (ws_size >= need_split);

    hipMemsetAsync(cnt, 0, 20000 * sizeof(int), stream);   // cnt+fill

    prep_kernel<<<7572, 256, 0, stream>>>(
        nf, Wnl0, Wnl1, Wfc1, Wfc2, eidx, st_vt16, W1T, W2T, cnt);

    scan_kernel<<<1, 1024, 0, stream>>>(cnt, row_start);
    scatter_kernel<<<(N_EDGES + 255) / 256, 256, 0, stream>>>(
        eidx, ea, row_start, fill, order, src_srt, dst_srt, sh_srt);

    if (use_split) {
        edge_mlp<<<NBLK, 256, 0, stream>>>(W1T, W2T, order, ef, w_srt);
        node_msg<<<N_NODES, 256, 0, stream>>>(
            row_start, dst_srt, sh_srt, w_srt, st_vt16,
            nf, Wskip0, Wskip1, Wout_s, Wout_v, out);
    } else {
        hipMemsetAsync(agg, 0, (size_t)N_NODES * 480 * sizeof(float), stream);
        edge_conv_fused<<<NBLK, 256, 0, stream>>>(
            W1T, W2T, order, src_srt, dst_srt, sh_srt, ef, st_vt16, agg);
        out_kernel<<<N_NODES, 128, 0, stream>>>(
            agg, nf, Wskip0, Wskip1, Wout_s, Wout_v, out);
    }
}

// Round 11
// 272.444 us; speedup vs baseline: 1.1226x; 1.1226x over previous
//
#include <hip/hip_runtime.h>
#include <math.h>

#define N_NODES 10000
#define N_EDGES 320000
#define TILES 5                 // edge_mlp: 5 tiles x 32 edges per block
#define NBLK (N_EDGES / (32 * TILES))   // 2000 blocks

#define SQRT3F     1.7320508075688772f
#define INV_SQRT3F 0.5773502691896258f
#define INV_SQRT2F 0.7071067811865476f

typedef short bf16x8 __attribute__((ext_vector_type(8)));
typedef short b16x4  __attribute__((ext_vector_type(4)));
typedef float f32x4  __attribute__((ext_vector_type(4)));
typedef unsigned int u32;

static __device__ __forceinline__ unsigned short f2b(float f) {
    unsigned int u = __float_as_uint(f);
    unsigned int r = (u + 0x7fffu + ((u >> 16) & 1u)) >> 16;   // RNE
    return (unsigned short)r;
}
static __device__ __forceinline__ float b2f(unsigned short h) {
    return __uint_as_float(((unsigned int)h) << 16);
}

// direct global->LDS 16B copy (lane-linear dest: base + lane*16)
static __device__ __forceinline__ void gl_lds16(const void* g, void* l) {
    __builtin_amdgcn_global_load_lds(
        (const __attribute__((address_space(1))) u32*)g,
        (__attribute__((address_space(3))) u32*)l,
        16, 0, 0);
}

// ---------------------------------------------------------------------------
// Kernel P: merged prep.
//  b < 6250   : node transforms -> st_vt32 (f32) and st_vt16 (bf16, fallback)
//  b < 7500   : src histogram
//  b < 7572   : W1T / W2T (edge-MLP weights, transposed bf16)
//  b < 7652   : WsCombT[96][160] = [Wout_s; Wskip0]^T, WvCombT[32][160] =
//               [Wout_v; Wskip1]^T  (out_gemm weights, bf16)
// ---------------------------------------------------------------------------
__global__ __launch_bounds__(256) void prep_kernel(
    const float* __restrict__ nf,
    const float* __restrict__ Wnl0,
    const float* __restrict__ Wnl1,
    const float* __restrict__ Wfc1,
    const float* __restrict__ Wfc2,
    const float* __restrict__ Wout_s,
    const float* __restrict__ Wout_v,
    const float* __restrict__ Wskip0,
    const float* __restrict__ Wskip1,
    const int* __restrict__ eidx,
    float* __restrict__ st_vt32,
    unsigned short* __restrict__ st_vt16,
    unsigned short* __restrict__ W1T,
    unsigned short* __restrict__ W2T,
    unsigned short* __restrict__ WsCombT,
    unsigned short* __restrict__ WvCombT,
    int* __restrict__ cnt)
{
    const int b = blockIdx.x;
    const int tid = threadIdx.x;
    if (b < 6250) {
        int gid = b * 256 + tid;
        if (gid >= N_NODES * 160) return;
        int n = gid / 160;
        int j = gid - n * 160;
        const float* nfn = nf + (size_t)n * 160;
        float acc = 0.f;
        if (j < 64) {
            #pragma unroll 8
            for (int k = 0; k < 64; ++k) acc += nfn[k] * Wnl0[k * 64 + j];
        } else {
            int t = j - 64;
            int i = t >> 5, k = t & 31;
            #pragma unroll 8
            for (int m = 0; m < 32; ++m) acc += nfn[64 + m * 3 + i] * Wnl1[m * 32 + k];
        }
        st_vt32[(size_t)n * 160 + j] = acc;
        st_vt16[(size_t)n * 160 + j] = f2b(acc);
    } else if (b < 7500) {
        int e = (b - 6250) * 256 + tid;
        if (e < N_EDGES) atomicAdd(&cnt[eidx[e]], 1);
    } else if (b < 7572) {
        int idx = (b - 7500) * 256 + tid;
        if (idx < 4096) {
            int n = idx >> 6, k = idx & 63;
            W1T[idx] = f2b(Wfc1[k * 64 + n]);
        } else if (idx < 18432) {
            int j = idx - 4096;
            int n = j >> 6, k = j & 63;
            W2T[j] = f2b(Wfc2[k * 224 + n]);
        }
    } else {
        int idx = (b - 7572) * 256 + tid;
        if (idx < 15360) {
            int n = idx / 160, k = idx - n * 160;
            float v = (k < 96) ? Wout_s[k * 96 + n] : Wskip0[(k - 96) * 96 + n];
            WsCombT[idx] = f2b(v);
        } else if (idx < 20480) {
            int j = idx - 15360;
            int n = j / 160, k = j - n * 160;
            float v = (k < 128) ? Wout_v[k * 32 + n] : Wskip1[(k - 128) * 32 + n];
            WvCombT[j] = f2b(v);
        }
    }
}

// ---------------------------------------------------------------------------
// scan + scatter (sorting by src)
// ---------------------------------------------------------------------------
__global__ __launch_bounds__(1024) void scan_kernel(
    const int* __restrict__ cnt, int* __restrict__ row_start)
{
    __shared__ int part[1024];
    const int t = threadIdx.x;
    const int CH = 10;
    int base = t * CH;
    int s = 0;
    for (int i = 0; i < CH; ++i) {
        int idx = base + i;
        if (idx < N_NODES) s += cnt[idx];
    }
    part[t] = s;
    __syncthreads();
    for (int off = 1; off < 1024; off <<= 1) {
        int v = (t >= off) ? part[t - off] : 0;
        __syncthreads();
        part[t] += v;
        __syncthreads();
    }
    int run = (t == 0) ? 0 : part[t - 1];
    for (int i = 0; i < CH; ++i) {
        int idx = base + i;
        if (idx < N_NODES) { row_start[idx] = run; run += cnt[idx]; }
    }
    if (t == 1023) row_start[N_NODES] = run;
}

__global__ __launch_bounds__(256) void scatter_kernel(
    const int* __restrict__ eidx, const float* __restrict__ edge_attr,
    const int* __restrict__ row_start,
    int* __restrict__ fill, int* __restrict__ order,
    int* __restrict__ src_srt, int* __restrict__ dst_srt,
    float* __restrict__ sh_srt)
{
    int e = blockIdx.x * 256 + threadIdx.x;
    if (e >= N_EDGES) return;
    int s = eidx[e];
    int p = atomicAdd(&fill[s], 1) + row_start[s];
    order[p] = e;
    src_srt[p] = s;
    dst_srt[p] = eidx[N_EDGES + e];
    float x = edge_attr[(size_t)e * 3 + 0];
    float y = edge_attr[(size_t)e * 3 + 1];
    float z = edge_attr[(size_t)e * 3 + 2];
    float inv = SQRT3F / sqrtf(x * x + y * y + z * z);
    sh_srt[(size_t)p * 4 + 0] = x * inv;
    sh_srt[(size_t)p * 4 + 1] = y * inv;
    sh_srt[(size_t)p * 4 + 2] = z * inv;
    sh_srt[(size_t)p * 4 + 3] = 0.f;
}

// ---------------------------------------------------------------------------
// Kernel A: pure MFMA MLP pipeline. Writes w_srt[p][224] bf16 coalesced.
// ---------------------------------------------------------------------------
__global__ __launch_bounds__(256, 5) void edge_mlp(
    const unsigned short* __restrict__ W1T,
    const unsigned short* __restrict__ W2T,
    const int* __restrict__ order,
    const float* __restrict__ edge_feature,
    unsigned short* __restrict__ w_srt)
{
    __shared__ __align__(16) unsigned short A1[32 * 64];      // 4 KB (swizzled)
    __shared__ __align__(16) unsigned short Hs[32 * 64];      // 4 KB (swizzled)
    __shared__ __align__(16) unsigned short w_s[32 * 224];    // 14 KB
    __shared__ int eid_s[160];

    const int tid  = threadIdx.x;
    const int lane = tid & 63;
    const int wv   = tid >> 6;
    const int l15  = lane & 15;
    const int g    = lane >> 4;
    const int p0   = blockIdx.x * (32 * TILES);

    bf16x8 w1b0 = *reinterpret_cast<const bf16x8*>(&W1T[(wv * 16 + l15) * 64 + g * 8]);
    bf16x8 w1b1 = *reinterpret_cast<const bf16x8*>(&W1T[(wv * 16 + l15) * 64 + 32 + g * 8]);
    bf16x8 w2b0[4], w2b1[4];
    #pragma unroll
    for (int ii = 0; ii < 4; ++ii) {
        int nt = wv * 4 + ii;
        w2b0[ii] = *reinterpret_cast<const bf16x8*>(&W2T[(nt * 16 + l15) * 64 + g * 8]);
        w2b1[ii] = *reinterpret_cast<const bf16x8*>(&W2T[(nt * 16 + l15) * 64 + 32 + g * 8]);
    }

    if (tid < 32 * TILES) eid_s[tid] = order[p0 + tid];
    __syncthreads();

    f32x4 efr[2];
    auto load_ef = [&](int t) {
        int ebase = t * 32;
        #pragma unroll
        for (int r = 0; r < 2; ++r) {
            int q = tid + r * 256;
            int el = q >> 4, qf = q & 15;
            efr[r] = *reinterpret_cast<const f32x4*>(
                edge_feature + (size_t)eid_s[ebase + el] * 64 + qf * 4);
        }
    };
    auto write_ef = [&]() {
        #pragma unroll
        for (int r = 0; r < 2; ++r) {
            int q = tid + r * 256;
            int el = q >> 4, f0 = (q & 15) * 4;
            b16x4 h;
            #pragma unroll
            for (int j = 0; j < 4; ++j) h[j] = (short)f2b(efr[r][j]);
            *reinterpret_cast<b16x4*>(&A1[el * 64 + (f0 ^ ((el & 7) << 3))]) = h;
        }
    };

    load_ef(0);

    for (int t = 0; t < TILES; ++t) {
        write_ef();
        __syncthreads();
        if (t < TILES - 1) load_ef(t + 1);

        // GEMM1: Hs = relu(A1 @ Wfc1)
        {
            const int nt = wv;
            #pragma unroll
            for (int mt = 0; mt < 2; ++mt) {
                f32x4 c4 = {0.f, 0.f, 0.f, 0.f};
                int ra = mt * 16 + l15;
                int sw = (ra & 7) << 3;
                bf16x8 a0 = *reinterpret_cast<const bf16x8*>(&A1[ra * 64 + ((g * 8) ^ sw)]);
                bf16x8 a1 = *reinterpret_cast<const bf16x8*>(&A1[ra * 64 + ((32 + g * 8) ^ sw)]);
                c4 = __builtin_amdgcn_mfma_f32_16x16x32_bf16(a0, w1b0, c4, 0, 0, 0);
                c4 = __builtin_amdgcn_mfma_f32_16x16x32_bf16(a1, w1b1, c4, 0, 0, 0);
                #pragma unroll
                for (int r = 0; r < 4; ++r) {
                    int row = mt * 16 + g * 4 + r;
                    int col = nt * 16 + l15;
                    Hs[row * 64 + (col ^ ((row & 7) << 3))] = f2b(fmaxf(c4[r], 0.f));
                }
            }
        }
        __syncthreads();

        // GEMM2: w_s = Hs @ Wfc2 (stores masked nt<14)
        {
            #pragma unroll
            for (int ii = 0; ii < 4; ++ii) {
                int nt = wv * 4 + ii;
                #pragma unroll
                for (int mt = 0; mt < 2; ++mt) {
                    f32x4 c4 = {0.f, 0.f, 0.f, 0.f};
                    int ra = mt * 16 + l15;
                    int sw = (ra & 7) << 3;
                    bf16x8 a0 = *reinterpret_cast<const bf16x8*>(&Hs[ra * 64 + ((g * 8) ^ sw)]);
                    bf16x8 a1 = *reinterpret_cast<const bf16x8*>(&Hs[ra * 64 + ((32 + g * 8) ^ sw)]);
                    c4 = __builtin_amdgcn_mfma_f32_16x16x32_bf16(a0, w2b0[ii], c4, 0, 0, 0);
                    c4 = __builtin_amdgcn_mfma_f32_16x16x32_bf16(a1, w2b1[ii], c4, 0, 0, 0);
                    if (nt < 14) {
                        #pragma unroll
                        for (int r = 0; r < 4; ++r) {
                            int row = mt * 16 + g * 4 + r;
                            w_s[row * 224 + nt * 16 + l15] = f2b(c4[r]);
                        }
                    }
                }
            }
        }
        __syncthreads();

        // coalesced copy-out: 32x224 u16 = 896 x 16B
        {
            const size_t gbase = (size_t)(p0 + t * 32) * 224;
            for (int idx = tid; idx < 896; idx += 256) {
                *reinterpret_cast<f32x4*>(&w_srt[gbase + idx * 8]) =
                    *reinterpret_cast<const f32x4*>(&w_s[idx * 8]);
            }
        }
    }
}

// ---------------------------------------------------------------------------
// Kernel B: per-NODE messages, v3. Messages only; writes agg[n][480] coalesced
// (no atomics, no epilogue). df staged as F32 (no x-conversions in the loop);
// w read directly from global (stream-once rows). LDS ~23 KB -> 7 blocks/CU.
// agg layout (PERMUTED vector regions, i-major):
//   [0:64) 0a | [64:96) 0b | [96:288) 1a: 96+i*64+c | [288:384) 1b | [384:480) 1c
// ---------------------------------------------------------------------------
__global__ __launch_bounds__(256, 7) void node_msg(
    const int* __restrict__ row_start,
    const int* __restrict__ dst_srt,
    const float* __restrict__ sh_srt,
    const unsigned short* __restrict__ w_srt,
    const float* __restrict__ st_vt32,
    float* __restrict__ agg)
{
    __shared__ __align__(16) float df[32 * 160];   // 20480 B (f32)
    __shared__ float aggbuf[480];
    __shared__ float sh_c[32][4];

    // chunked XCD remap (10000 = 8 * 1250)
    const int n   = (blockIdx.x & 7) * 1250 + (blockIdx.x >> 3);
    const int tid = threadIdx.x;
    const int p_start = row_start[n];
    const int p_end   = row_start[n + 1];

    const int tid2 = tid & 127;
    const int half = tid >> 7;
    int region, cb, iv;
    if (tid2 < 48)       { region = 0; cb = tid2 & 15;        iv = tid2 >> 4; }
    else if (tid2 < 64)  { region = 1; cb = tid2 - 48;        iv = 0; }
    else if (tid2 < 88)  { region = 2; cb = (tid2 - 64) & 7;  iv = (tid2 - 64) >> 3; }
    else if (tid2 < 112) { region = 3; cb = (tid2 - 88) & 7;  iv = (tid2 - 88) >> 3; }
    else if (tid2 < 120) { region = 4; cb = tid2 - 112;       iv = 0; }
    else                 { region = 5; cb = 0; iv = 0; }
    int rbase = 0, woff = 0, doff = 0;
    if (region == 0)      { rbase = 96 + iv * 64 + 4 * cb;  woff = 64 + 4 * cb;  doff = 4 * cb; }
    else if (region == 1) { rbase = 4 * cb;                 woff = 4 * cb;       doff = 4 * cb; }
    else if (region == 2) { rbase = 288 + iv * 32 + 4 * cb; woff = 128 + 4 * cb; doff = 64 + iv * 32 + 4 * cb; }
    else if (region == 3) { rbase = 384 + iv * 32 + 4 * cb; woff = 192 + 4 * cb; }
    else if (region == 4) { rbase = 64 + 4 * cb;            woff = 160 + 4 * cb; }
    int i1 = iv + 1; if (i1 == 3) i1 = 0;
    int i2 = 3 - iv - i1;

    f32x4 acc = {0.f, 0.f, 0.f, 0.f};

    for (int pb = p_start; pb < p_end; pb += 32) {
        __syncthreads();                       // df/sh_c reuse guard

        if (tid < 32) {
            int pp = min(pb + tid, p_end - 1);
            *reinterpret_cast<f32x4*>(&sh_c[tid][0]) =
                *reinterpret_cast<const f32x4*>(&sh_srt[(size_t)pp * 4]);
        }
        // stage df f32: 1280 x 16B (exactly 5 full rounds of 256)
        #pragma unroll
        for (int r = 0; r < 5; ++r) {
            int idx = tid + r * 256;
            int el = idx / 40, off = idx - el * 40;
            int pp = min(pb + el, p_end - 1);
            int d = dst_srt[pp];
            gl_lds16(st_vt32 + (size_t)d * 160 + off * 4, &df[idx * 4]);
        }
        __syncthreads();                       // vmcnt drained

        const int nvalid = p_end - pb;
        if (region < 5) {
            const int e0l = half * 16;
            #pragma unroll 4
            for (int j2 = 0; j2 < 16; ++j2) {
                int el = e0l + j2;
                if (el >= nvalid) break;       // uniform per half
                const float* dfp = &df[el * 160];
                const unsigned short* we = w_srt + (size_t)(pb + el) * 224;  // GLOBAL
                b16x4 w = *reinterpret_cast<const b16x4*>(we + woff);
                if (region == 0) {
                    f32x4 x = *reinterpret_cast<const f32x4*>(dfp + doff);
                    float sh = sh_c[el][iv];
                    #pragma unroll
                    for (int j = 0; j < 4; ++j)
                        acc[j] += b2f((unsigned short)w[j]) * x[j] * sh;
                } else if (region == 1 || region == 2) {
                    f32x4 x = *reinterpret_cast<const f32x4*>(dfp + doff);
                    #pragma unroll
                    for (int j = 0; j < 4; ++j)
                        acc[j] += b2f((unsigned short)w[j]) * x[j];
                } else if (region == 3) {
                    f32x4 xA = *reinterpret_cast<const f32x4*>(dfp + 64 + i1 * 32 + 4 * cb);
                    f32x4 xB = *reinterpret_cast<const f32x4*>(dfp + 64 + i2 * 32 + 4 * cb);
                    float shA = sh_c[el][i1], shB = sh_c[el][i2];
                    #pragma unroll
                    for (int j = 0; j < 4; ++j)
                        acc[j] += b2f((unsigned short)w[j]) *
                                  (xA[j] * shB - xB[j] * shA) * INV_SQRT2F;
                } else {
                    f32x4 x0 = *reinterpret_cast<const f32x4*>(dfp + 64 + 4 * cb);
                    f32x4 x1 = *reinterpret_cast<const f32x4*>(dfp + 96 + 4 * cb);
                    f32x4 x2 = *reinterpret_cast<const f32x4*>(dfp + 128 + 4 * cb);
                    float s0 = sh_c[el][0], s1 = sh_c[el][1], s2 = sh_c[el][2];
                    #pragma unroll
                    for (int j = 0; j < 4; ++j)
                        acc[j] += b2f((unsigned short)w[j]) *
                                  (x0[j] * s0 + x1[j] * s1 + x2[j] * s2) * INV_SQRT3F;
                }
            }
        }
    }

    // combine halves into aggbuf, write agg coalesced
    __syncthreads();
    if (half == 0 && region < 5) {
        #pragma unroll
        for (int j = 0; j < 4; ++j) aggbuf[rbase + j] = acc[j];
    }
    __syncthreads();
    if (half == 1 && region < 5) {
        #pragma unroll
        for (int j = 0; j < 4; ++j) aggbuf[rbase + j] += acc[j];
    }
    __syncthreads();
    if (tid < 120) {
        *reinterpret_cast<f32x4*>(&agg[(size_t)n * 480 + tid * 4]) =
            *reinterpret_cast<const f32x4*>(&aggbuf[tid * 4]);
    }
}

// ---------------------------------------------------------------------------
// Kernel C: out_gemm. 32 nodes/block, 4 waves, MFMA K=160 fused transforms:
//   os[32][96] = [agg_s/32 | nf_s] @ [Wout_s; Wskip0]    (12 16x16 tiles)
//   ov[i][32][32] = [agg_v_i/32 | nf_v_i] @ [Wout_v; Wskip1]  (12 tiles)
// then silu/sigmoid-gate epilogue, final out[n][160].
// ---------------------------------------------------------------------------
__global__ __launch_bounds__(256) void out_gemm(
    const float* __restrict__ agg,
    const float* __restrict__ nf,
    const unsigned short* __restrict__ WsCombT,
    const unsigned short* __restrict__ WvCombT,
    float* __restrict__ out)
{
    __shared__ float os_l[32][96];       // 12 KB
    __shared__ float ov_l[3][32][32];    // 12 KB

    const int n0  = blockIdx.x * 32;
    const int tid = threadIdx.x;
    const int lane = tid & 63;
    const int wv   = tid >> 6;
    const int l15  = lane & 15;
    const int g    = lane >> 4;

    #pragma unroll
    for (int jj = 0; jj < 6; ++jj) {
        int job = wv * 6 + jj;          // 0..23
        bool isS;
        int mt, nt, ii = 0;
        if (job < 12) { isS = true;  mt = job & 1; nt = job >> 1; }
        else { int j = job - 12; isS = false; ii = j >> 2; mt = (j >> 1) & 1; nt = j & 1; }

        int ra = mt * 16 + l15;
        int n  = min(n0 + ra, N_NODES - 1);
        const float* aggn = agg + (size_t)n * 480;
        const float* nfn  = nf + (size_t)n * 160;
        const unsigned short* WT = isS ? WsCombT : WvCombT;

        f32x4 c4 = {0.f, 0.f, 0.f, 0.f};
        #pragma unroll
        for (int kk = 0; kk < 5; ++kk) {
            int k0 = kk * 32 + g * 8;
            float av[8];
            if (isS) {
                if (k0 < 96) {
                    f32x4 p0 = *reinterpret_cast<const f32x4*>(aggn + k0);
                    f32x4 p1 = *reinterpret_cast<const f32x4*>(aggn + k0 + 4);
                    #pragma unroll
                    for (int j = 0; j < 4; ++j) { av[j] = p0[j] * (1.f/32.f); av[4+j] = p1[j] * (1.f/32.f); }
                } else {
                    f32x4 p0 = *reinterpret_cast<const f32x4*>(nfn + (k0 - 96));
                    f32x4 p1 = *reinterpret_cast<const f32x4*>(nfn + (k0 - 96) + 4);
                    #pragma unroll
                    for (int j = 0; j < 4; ++j) { av[j] = p0[j]; av[4+j] = p1[j]; }
                }
            } else {
                if (k0 < 128) {
                    int base = (k0 < 64) ? (96 + ii * 64 + k0)
                             : (k0 < 96) ? (288 + ii * 32 + (k0 - 64))
                                         : (384 + ii * 32 + (k0 - 96));
                    f32x4 p0 = *reinterpret_cast<const f32x4*>(aggn + base);
                    f32x4 p1 = *reinterpret_cast<const f32x4*>(aggn + base + 4);
                    #pragma unroll
                    for (int j = 0; j < 4; ++j) { av[j] = p0[j] * (1.f/32.f); av[4+j] = p1[j] * (1.f/32.f); }
                } else {
                    #pragma unroll
                    for (int j = 0; j < 8; ++j)
                        av[j] = nfn[64 + (k0 - 128 + j) * 3 + ii];
                }
            }
            bf16x8 a;
            #pragma unroll
            for (int j = 0; j < 8; ++j) a[j] = (short)f2b(av[j]);
            bf16x8 bfr = *reinterpret_cast<const bf16x8*>(
                WT + (size_t)(nt * 16 + l15) * 160 + k0);
            c4 = __builtin_amdgcn_mfma_f32_16x16x32_bf16(a, bfr, c4, 0, 0, 0);
        }
        #pragma unroll
        for (int r = 0; r < 4; ++r) {
            int row = mt * 16 + g * 4 + r;
            int col = nt * 16 + l15;
            if (isS) os_l[row][col] = c4[r];
            else     ov_l[ii][row][col] = c4[r];
        }
    }
    __syncthreads();

    // epilogue: 32 nodes x 160 outputs
    for (int idx = tid; idx < 32 * 160; idx += 256) {
        int r = idx / 160, c = idx - r * 160;
        int n = n0 + r;
        if (n < N_NODES) {
            if (c < 64) {
                float x = os_l[r][c];
                out[(size_t)n * 160 + c] = x / (1.f + expf(-x));      // silu
            } else {
                int t = c - 64;
                int k = t / 3, i = t - 3 * k;
                float gg = os_l[r][64 + k];
                gg = 1.f / (1.f + expf(-gg));                          // sigmoid
                out[(size_t)n * 160 + c] = gg * ov_l[i][r][k];
            }
        }
    }
}

// ---------------------------------------------------------------------------
// Fallback path (only if ws can't hold w_srt): round-6 fused kernel + out.
// ---------------------------------------------------------------------------
__global__ __launch_bounds__(256, 3) void edge_conv_fused(
    const unsigned short* __restrict__ W1T,
    const unsigned short* __restrict__ W2T,
    const int* __restrict__ order,
    const int* __restrict__ src_srt,
    const int* __restrict__ dst_srt,
    const float* __restrict__ sh_srt,
    const float* __restrict__ edge_feature,
    const unsigned short* __restrict__ st_vt16,
    float* __restrict__ agg)
{
    __shared__ __align__(16) unsigned short A1[32 * 64];
    __shared__ __align__(16) unsigned short Hs[32 * 64];
    __shared__ __align__(16) unsigned short w_s[32 * 224];
    __shared__ __align__(16) unsigned short df[2][32 * 160];
    __shared__ int   eid_s[160];
    __shared__ int   src_s[160];
    __shared__ int   dst_s[160];
    __shared__ float sh_s[160][4];

    const int tid  = threadIdx.x;
    const int lane = tid & 63;
    const int wv   = tid >> 6;
    const int l15  = lane & 15;
    const int g    = lane >> 4;
    const int p0   = blockIdx.x * (32 * TILES);

    bf16x8 w1b0 = *reinterpret_cast<const bf16x8*>(&W1T[(wv * 16 + l15) * 64 + g * 8]);
    bf16x8 w1b1 = *reinterpret_cast<const bf16x8*>(&W1T[(wv * 16 + l15) * 64 + 32 + g * 8]);
    bf16x8 w2b0[4], w2b1[4];
    #pragma unroll
    for (int ii = 0; ii < 4; ++ii) {
        int nt = wv * 4 + ii;
        w2b0[ii] = *reinterpret_cast<const bf16x8*>(&W2T[(nt * 16 + l15) * 64 + g * 8]);
        w2b1[ii] = *reinterpret_cast<const bf16x8*>(&W2T[(nt * 16 + l15) * 64 + 32 + g * 8]);
    }

    if (tid < 32 * TILES) {
        int p = p0 + tid;
        eid_s[tid] = order[p];
        src_s[tid] = src_srt[p];
        dst_s[tid] = dst_srt[p];
        *reinterpret_cast<f32x4*>(&sh_s[tid][0]) =
            *reinterpret_cast<const f32x4*>(&sh_srt[(size_t)p * 4]);
    }
    __syncthreads();

    const int tid2 = tid & 127;
    int region, cb, iv;
    if (tid2 < 48)       { region = 0; cb = tid2 & 15;        iv = tid2 >> 4; }
    else if (tid2 < 64)  { region = 1; cb = tid2 - 48;        iv = 0; }
    else if (tid2 < 88)  { region = 2; cb = (tid2 - 64) & 7;  iv = (tid2 - 64) >> 3; }
    else if (tid2 < 112) { region = 3; cb = (tid2 - 88) & 7;  iv = (tid2 - 88) >> 3; }
    else if (tid2 < 120) { region = 4; cb = tid2 - 112;       iv = 0; }
    else                 { region = 5; cb = 0; iv = 0; }
    int rbase = 0, woff = 0, doff = 0;
    if (region == 0)      { rbase = 96 + iv * 64 + 4 * cb;  woff = 64 + 4 * cb;  doff = 4 * cb; }
    else if (region == 1) { rbase = 4 * cb;                 woff = 4 * cb;       doff = 4 * cb; }
    else if (region == 2) { rbase = 288 + iv * 32 + 4 * cb; woff = 128 + 4 * cb; doff = 64 + iv * 32 + 4 * cb; }
    else if (region == 3) { rbase = 384 + iv * 32 + 4 * cb; woff = 192 + 4 * cb; }
    else if (region == 4) { rbase = 64 + 4 * cb;            woff = 160 + 4 * cb; }
    int i1 = iv + 1; if (i1 == 3) i1 = 0;
    int i2 = 3 - iv - i1;

    f32x4 acc = {0.f, 0.f, 0.f, 0.f};
    int cur = src_s[(tid >> 7) * 16];

    f32x4 efr[2];
    auto load_ef = [&](int t) {
        int ebase = t * 32;
        #pragma unroll
        for (int r = 0; r < 2; ++r) {
            int q = tid + r * 256;
            int el = q >> 4, qf = q & 15;
            efr[r] = *reinterpret_cast<const f32x4*>(
                edge_feature + (size_t)eid_s[ebase + el] * 64 + qf * 4);
        }
    };
    auto write_ef = [&]() {
        #pragma unroll
        for (int r = 0; r < 2; ++r) {
            int q = tid + r * 256;
            int el = q >> 4, f0 = (q & 15) * 4;
            b16x4 h;
            #pragma unroll
            for (int j = 0; j < 4; ++j) h[j] = (short)f2b(efr[r][j]);
            *reinterpret_cast<b16x4*>(&A1[el * 64 + (f0 ^ ((el & 7) << 3))]) = h;
        }
    };
    auto issue_df = [&](int t, int b) {
        int ebase = t * 32;
        #pragma unroll
        for (int r = 0; r < 3; ++r) {
            int idx = tid + r * 256;
            if (idx < 640) {
                int el = idx / 20, off = idx - el * 20;
                gl_lds16(st_vt16 + (size_t)dst_s[ebase + el] * 160 + off * 8,
                         &df[b][idx * 8]);
            }
        }
    };

    issue_df(0, 0);
    load_ef(0);

    for (int t = 0; t < TILES; ++t) {
        const int b = t & 1;
        write_ef();
        __syncthreads();
        if (t < TILES - 1) {
            issue_df(t + 1, b ^ 1);
            load_ef(t + 1);
        }
        {
            const int nt = wv;
            #pragma unroll
            for (int mt = 0; mt < 2; ++mt) {
                f32x4 c4 = {0.f, 0.f, 0.f, 0.f};
                int ra = mt * 16 + l15;
                int sw = (ra & 7) << 3;
                bf16x8 a0 = *reinterpret_cast<const bf16x8*>(&A1[ra * 64 + ((g * 8) ^ sw)]);
                bf16x8 a1 = *reinterpret_cast<const bf16x8*>(&A1[ra * 64 + ((32 + g * 8) ^ sw)]);
                c4 = __builtin_amdgcn_mfma_f32_16x16x32_bf16(a0, w1b0, c4, 0, 0, 0);
                c4 = __builtin_amdgcn_mfma_f32_16x16x32_bf16(a1, w1b1, c4, 0, 0, 0);
                #pragma unroll
                for (int r = 0; r < 4; ++r) {
                    int row = mt * 16 + g * 4 + r;
                    int col = nt * 16 + l15;
                    Hs[row * 64 + (col ^ ((row & 7) << 3))] = f2b(fmaxf(c4[r], 0.f));
                }
            }
        }
        __syncthreads();
        {
            #pragma unroll
            for (int ii = 0; ii < 4; ++ii) {
                int nt = wv * 4 + ii;
                #pragma unroll
                for (int mt = 0; mt < 2; ++mt) {
                    f32x4 c4 = {0.f, 0.f, 0.f, 0.f};
                    int ra = mt * 16 + l15;
                    int sw = (ra & 7) << 3;
                    bf16x8 a0 = *reinterpret_cast<const bf16x8*>(&Hs[ra * 64 + ((g * 8) ^ sw)]);
                    bf16x8 a1 = *reinterpret_cast<const bf16x8*>(&Hs[ra * 64 + ((32 + g * 8) ^ sw)]);
                    c4 = __builtin_amdgcn_mfma_f32_16x16x32_bf16(a0, w2b0[ii], c4, 0, 0, 0);
                    c4 = __builtin_amdgcn_mfma_f32_16x16x32_bf16(a1, w2b1[ii], c4, 0, 0, 0);
                    if (nt < 14) {
                        #pragma unroll
                        for (int r = 0; r < 4; ++r) {
                            int row = mt * 16 + g * 4 + r;
                            w_s[row * 224 + nt * 16 + l15] = f2b(c4[r]);
                        }
                    }
                }
            }
        }
        __syncthreads();
        if (region < 5) {
            const int e0l = (tid >> 7) * 16;
            #pragma unroll 4
            for (int j2 = 0; j2 < 16; ++j2) {
                int el = e0l + j2;
                int eg = t * 32 + el;
                int s = src_s[eg];
                if (s != cur) {
                    #pragma unroll
                    for (int j = 0; j < 4; ++j)
                        atomicAdd(&agg[(size_t)cur * 480 + rbase + j], acc[j]);
                    acc = (f32x4){0.f, 0.f, 0.f, 0.f};
                    cur = s;
                }
                const unsigned short* dfp = &df[b][el * 160];
                const unsigned short* we  = &w_s[el * 224];
                b16x4 w = *reinterpret_cast<const b16x4*>(we + woff);
                if (region == 0) {
                    b16x4 x = *reinterpret_cast<const b16x4*>(dfp + doff);
                    float sh = sh_s[eg][iv];
                    #pragma unroll
                    for (int j = 0; j < 4; ++j)
                        acc[j] += b2f((unsigned short)w[j]) * b2f((unsigned short)x[j]) * sh;
                } else if (region == 1 || region == 2) {
                    b16x4 x = *reinterpret_cast<const b16x4*>(dfp + doff);
                    #pragma unroll
                    for (int j = 0; j < 4; ++j)
                        acc[j] += b2f((unsigned short)w[j]) * b2f((unsigned short)x[j]);
                } else if (region == 3) {
                    b16x4 xA = *reinterpret_cast<const b16x4*>(dfp + 64 + i1 * 32 + 4 * cb);
                    b16x4 xB = *reinterpret_cast<const b16x4*>(dfp + 64 + i2 * 32 + 4 * cb);
                    float shA = sh_s[eg][i1], shB = sh_s[eg][i2];
                    #pragma unroll
                    for (int j = 0; j < 4; ++j)
                        acc[j] += b2f((unsigned short)w[j]) *
                                  (b2f((unsigned short)xA[j]) * shB -
                                   b2f((unsigned short)xB[j]) * shA) * INV_SQRT2F;
                } else {
                    b16x4 x0 = *reinterpret_cast<const b16x4*>(dfp + 64 + 4 * cb);
                    b16x4 x1 = *reinterpret_cast<const b16x4*>(dfp + 96 + 4 * cb);
                    b16x4 x2 = *reinterpret_cast<const b16x4*>(dfp + 128 + 4 * cb);
                    float s0 = sh_s[eg][0], s1 = sh_s[eg][1], s2 = sh_s[eg][2];
                    #pragma unroll
                    for (int j = 0; j < 4; ++j)
                        acc[j] += b2f((unsigned short)w[j]) *
                                  (b2f((unsigned short)x0[j]) * s0 +
                                   b2f((unsigned short)x1[j]) * s1 +
                                   b2f((unsigned short)x2[j]) * s2) * INV_SQRT3F;
                }
            }
        }
    }
    if (region < 5) {
        #pragma unroll
        for (int j = 0; j < 4; ++j)
            atomicAdd(&agg[(size_t)cur * 480 + rbase + j], acc[j]);
    }
}

__global__ __launch_bounds__(128) void out_kernel(
    const float* __restrict__ agg,
    const float* __restrict__ nf,
    const float* __restrict__ Wskip0,
    const float* __restrict__ Wskip1,
    const float* __restrict__ Wout_s,
    const float* __restrict__ Wout_v,
    float* __restrict__ out)
{
    __shared__ float aggl[480];
    __shared__ float os_s[96];
    const int n = blockIdx.x;
    const int tid = threadIdx.x;
    const float* nfn = nf + (size_t)n * 160;

    for (int idx = tid; idx < 480; idx += 128)
        aggl[idx] = agg[(size_t)n * 480 + idx] * (1.f / 32.f);
    __syncthreads();

    if (tid < 96) {
        float acc = 0.f;
        #pragma unroll 8
        for (int k = 0; k < 64; ++k) acc += nfn[k] * Wskip0[k * 96 + tid];
        for (int r = 0; r < 96; ++r) acc += aggl[r] * Wout_s[r * 96 + tid];
        os_s[tid] = acc;
    }
    __syncthreads();

    if (tid < 64) {
        float x = os_s[tid];
        out[(size_t)n * 160 + tid] = x / (1.f + expf(-x));
    }
    if (tid < 96) {
        int t = tid;
        int k = t / 3, i = t - 3 * k;
        float acc = 0.f;
        #pragma unroll 8
        for (int m = 0; m < 32; ++m) acc += nfn[64 + m * 3 + i] * Wskip1[m * 32 + k];
        #pragma unroll 8
        for (int m = 0; m < 64; ++m) acc += aggl[96 + i * 64 + m] * Wout_v[m * 32 + k];
        #pragma unroll 8
        for (int m = 0; m < 32; ++m) acc += aggl[288 + i * 32 + m] * Wout_v[(64 + m) * 32 + k];
        #pragma unroll 8
        for (int m = 0; m < 32; ++m) acc += aggl[384 + i * 32 + m] * Wout_v[(96 + m) * 32 + k];
        float g = os_s[64 + k];
        g = 1.f / (1.f + expf(-g));
        out[(size_t)n * 160 + 64 + t] = g * acc;
    }
}

// ---------------------------------------------------------------------------
extern "C" void kernel_launch(void* const* d_in, const int* in_sizes, int n_in,
                              void* d_out, int out_size, void* d_ws, size_t ws_size,
                              hipStream_t stream)
{
    const float* nf     = (const float*)d_in[0];
    const float* ea     = (const float*)d_in[1];
    const float* ef     = (const float*)d_in[2];
    const float* Wskip0 = (const float*)d_in[3];
    const float* Wskip1 = (const float*)d_in[4];
    const float* Wnl0   = (const float*)d_in[5];
    const float* Wnl1   = (const float*)d_in[6];
    const float* Wfc1   = (const float*)d_in[7];
    const float* Wfc2   = (const float*)d_in[8];
    const float* Wout_s = (const float*)d_in[9];
    const float* Wout_v = (const float*)d_in[10];
    const int*   eidx   = (const int*)d_in[11];
    float* out = (float*)d_out;

    // workspace layout (16B-aligned sections)
    int*   cnt       = (int*)d_ws;                        // 10000
    int*   fill      = cnt + 10000;                       // 10000
    int*   row_start = fill + 10000;                      // 10004
    int*   order     = row_start + 10004;                 // 320000
    int*   src_srt   = order + 320000;                    // 320000
    int*   dst_srt   = src_srt + 320000;                  // 320000
    float* sh_srt    = (float*)(dst_srt + 320000);        // 1,280,000
    float* agg       = sh_srt + 1280000;                  // 4,800,000
    float* st_vt32   = agg + 4800000;                     // 1,600,000
    unsigned short* st_vt16 = (unsigned short*)(st_vt32 + 1600000); // 1,600,000
    unsigned short* W1T     = st_vt16 + 1600000;          // 4,096
    unsigned short* W2T     = W1T + 4096;                 // 16,384
    unsigned short* WsCombT = W2T + 16384;                // 15,360
    unsigned short* WvCombT = WsCombT + 15360;            // 5,120 (+pad 32)
    unsigned short* w_srt   = WvCombT + 5152;             // (N_EDGES+32)*224

    const size_t need_split =
        (size_t)((const char*)(w_srt + (size_t)(N_EDGES + 32) * 224) - (const char*)d_ws);
    const bool use_split = (ws_size >= need_split);

    hipMemsetAsync(cnt, 0, 20000 * sizeof(int), stream);   // cnt+fill

    prep_kernel<<<7652, 256, 0, stream>>>(
        nf, Wnl0, Wnl1, Wfc1, Wfc2, Wout_s, Wout_v, Wskip0, Wskip1,
        eidx, st_vt32, st_vt16, W1T, W2T, WsCombT, WvCombT, cnt);

    scan_kernel<<<1, 1024, 0, stream>>>(cnt, row_start);
    scatter_kernel<<<(N_EDGES + 255) / 256, 256, 0, stream>>>(
        eidx, ea, row_start, fill, order, src_srt, dst_srt, sh_srt);

    if (use_split) {
        edge_mlp<<<NBLK, 256, 0, stream>>>(W1T, W2T, order, ef, w_srt);
        node_msg<<<N_NODES, 256, 0, stream>>>(
            row_start, dst_srt, sh_srt, w_srt, st_vt32, agg);
        out_gemm<<<(N_NODES + 31) / 32, 256, 0, stream>>>(
            agg, nf, WsCombT, WvCombT, out);
    } else {
        hipMemsetAsync(agg, 0, (size_t)N_NODES * 480 * sizeof(float), stream);
        edge_conv_fused<<<NBLK, 256, 0, stream>>>(
            W1T, W2T, order, src_srt, dst_srt, sh_srt, ef, st_vt16, agg);
        out_kernel<<<N_NODES, 128, 0, stream>>>(
            agg, nf, Wskip0, Wskip1, Wout_s, Wout_v, out);
    }
}

// Round 12
// 270.720 us; speedup vs baseline: 1.1298x; 1.0064x over previous
//
#include <hip/hip_runtime.h>
#include <math.h>

#define N_NODES 10000
#define N_EDGES 320000
#define TILES 8                 // edge_mlp: 8 tiles x 32 edges per block
#define NBLK (N_EDGES / (32 * TILES))   // 1250 blocks (one resident round)

#define SQRT3F     1.7320508075688772f
#define INV_SQRT3F 0.5773502691896258f
#define INV_SQRT2F 0.7071067811865476f

typedef short bf16x8 __attribute__((ext_vector_type(8)));
typedef short b16x4  __attribute__((ext_vector_type(4)));
typedef float f32x4  __attribute__((ext_vector_type(4)));
typedef unsigned int u32;

static __device__ __forceinline__ unsigned short f2b(float f) {
    unsigned int u = __float_as_uint(f);
    unsigned int r = (u + 0x7fffu + ((u >> 16) & 1u)) >> 16;   // RNE
    return (unsigned short)r;
}
static __device__ __forceinline__ float b2f(unsigned short h) {
    return __uint_as_float(((unsigned int)h) << 16);
}

// direct global->LDS 16B copy (lane-linear dest: base + lane*16).
// NOTE: when predicated, active lanes must form a PREFIX of the wave so the
// wave-uniform LDS base (taken from the first active lane) stays correct.
static __device__ __forceinline__ void gl_lds16(const void* g, void* l) {
    __builtin_amdgcn_global_load_lds(
        (const __attribute__((address_space(1))) u32*)g,
        (__attribute__((address_space(3))) u32*)l,
        16, 0, 0);
}

// ---------------------------------------------------------------------------
// Kernel P: merged prep.
//  b < 6250   : node transforms -> st_vt32 (f32) and st_vt16 (bf16, fallback)
//  b < 7500   : src histogram
//  b < 7572   : W1T / W2T (edge-MLP weights, transposed bf16)
//  b < 7652   : WsCombT[96][160], WvCombT[32][160] (out_gemm weights, bf16)
// ---------------------------------------------------------------------------
__global__ __launch_bounds__(256) void prep_kernel(
    const float* __restrict__ nf,
    const float* __restrict__ Wnl0,
    const float* __restrict__ Wnl1,
    const float* __restrict__ Wfc1,
    const float* __restrict__ Wfc2,
    const float* __restrict__ Wout_s,
    const float* __restrict__ Wout_v,
    const float* __restrict__ Wskip0,
    const float* __restrict__ Wskip1,
    const int* __restrict__ eidx,
    float* __restrict__ st_vt32,
    unsigned short* __restrict__ st_vt16,
    unsigned short* __restrict__ W1T,
    unsigned short* __restrict__ W2T,
    unsigned short* __restrict__ WsCombT,
    unsigned short* __restrict__ WvCombT,
    int* __restrict__ cnt)
{
    const int b = blockIdx.x;
    const int tid = threadIdx.x;
    if (b < 6250) {
        int gid = b * 256 + tid;
        if (gid >= N_NODES * 160) return;
        int n = gid / 160;
        int j = gid - n * 160;
        const float* nfn = nf + (size_t)n * 160;
        float acc = 0.f;
        if (j < 64) {
            #pragma unroll 8
            for (int k = 0; k < 64; ++k) acc += nfn[k] * Wnl0[k * 64 + j];
        } else {
            int t = j - 64;
            int i = t >> 5, k = t & 31;
            #pragma unroll 8
            for (int m = 0; m < 32; ++m) acc += nfn[64 + m * 3 + i] * Wnl1[m * 32 + k];
        }
        st_vt32[(size_t)n * 160 + j] = acc;
        st_vt16[(size_t)n * 160 + j] = f2b(acc);
    } else if (b < 7500) {
        int e = (b - 6250) * 256 + tid;
        if (e < N_EDGES) atomicAdd(&cnt[eidx[e]], 1);
    } else if (b < 7572) {
        int idx = (b - 7500) * 256 + tid;
        if (idx < 4096) {
            int n = idx >> 6, k = idx & 63;
            W1T[idx] = f2b(Wfc1[k * 64 + n]);
        } else if (idx < 18432) {
            int j = idx - 4096;
            int n = j >> 6, k = j & 63;
            W2T[j] = f2b(Wfc2[k * 224 + n]);
        }
    } else {
        int idx = (b - 7572) * 256 + tid;
        if (idx < 15360) {
            int n = idx / 160, k = idx - n * 160;
            float v = (k < 96) ? Wout_s[k * 96 + n] : Wskip0[(k - 96) * 96 + n];
            WsCombT[idx] = f2b(v);
        } else if (idx < 20480) {
            int j = idx - 15360;
            int n = j / 160, k = j - n * 160;
            float v = (k < 128) ? Wout_v[k * 32 + n] : Wskip1[(k - 128) * 32 + n];
            WvCombT[j] = f2b(v);
        }
    }
}

// ---------------------------------------------------------------------------
// scan + scatter (sorting by src)
// ---------------------------------------------------------------------------
__global__ __launch_bounds__(1024) void scan_kernel(
    const int* __restrict__ cnt, int* __restrict__ row_start)
{
    __shared__ int part[1024];
    const int t = threadIdx.x;
    const int CH = 10;
    int base = t * CH;
    int s = 0;
    for (int i = 0; i < CH; ++i) {
        int idx = base + i;
        if (idx < N_NODES) s += cnt[idx];
    }
    part[t] = s;
    __syncthreads();
    for (int off = 1; off < 1024; off <<= 1) {
        int v = (t >= off) ? part[t - off] : 0;
        __syncthreads();
        part[t] += v;
        __syncthreads();
    }
    int run = (t == 0) ? 0 : part[t - 1];
    for (int i = 0; i < CH; ++i) {
        int idx = base + i;
        if (idx < N_NODES) { row_start[idx] = run; run += cnt[idx]; }
    }
    if (t == 1023) row_start[N_NODES] = run;
}

__global__ __launch_bounds__(256) void scatter_kernel(
    const int* __restrict__ eidx, const float* __restrict__ edge_attr,
    const int* __restrict__ row_start,
    int* __restrict__ fill, int* __restrict__ order,
    int* __restrict__ src_srt, int* __restrict__ dst_srt,
    float* __restrict__ sh_srt)
{
    int e = blockIdx.x * 256 + threadIdx.x;
    if (e >= N_EDGES) return;
    int s = eidx[e];
    int p = atomicAdd(&fill[s], 1) + row_start[s];
    order[p] = e;
    src_srt[p] = s;
    dst_srt[p] = eidx[N_EDGES + e];
    float x = edge_attr[(size_t)e * 3 + 0];
    float y = edge_attr[(size_t)e * 3 + 1];
    float z = edge_attr[(size_t)e * 3 + 2];
    float inv = SQRT3F / sqrtf(x * x + y * y + z * z);
    sh_srt[(size_t)p * 4 + 0] = x * inv;
    sh_srt[(size_t)p * 4 + 1] = y * inv;
    sh_srt[(size_t)p * 4 + 2] = z * inv;
    sh_srt[(size_t)p * 4 + 3] = 0.f;
}

// ---------------------------------------------------------------------------
// Kernel A: pure MFMA MLP pipeline. Writes w_srt[p][224] bf16 coalesced.
// 1250 blocks (all resident in one round at 5+/CU); 8 tiles of 32 edges.
// ---------------------------------------------------------------------------
__global__ __launch_bounds__(256, 7) void edge_mlp(
    const unsigned short* __restrict__ W1T,
    const unsigned short* __restrict__ W2T,
    const int* __restrict__ order,
    const float* __restrict__ edge_feature,
    unsigned short* __restrict__ w_srt)
{
    __shared__ __align__(16) unsigned short A1[32 * 64];      // 4 KB (swizzled)
    __shared__ __align__(16) unsigned short Hs[32 * 64];      // 4 KB (swizzled)
    __shared__ __align__(16) unsigned short w_s[32 * 224];    // 14 KB
    __shared__ int eid_s[32 * TILES];

    const int tid  = threadIdx.x;
    const int lane = tid & 63;
    const int wv   = tid >> 6;
    const int l15  = lane & 15;
    const int g    = lane >> 4;
    const int p0   = blockIdx.x * (32 * TILES);

    bf16x8 w1b0 = *reinterpret_cast<const bf16x8*>(&W1T[(wv * 16 + l15) * 64 + g * 8]);
    bf16x8 w1b1 = *reinterpret_cast<const bf16x8*>(&W1T[(wv * 16 + l15) * 64 + 32 + g * 8]);
    bf16x8 w2b0[4], w2b1[4];
    #pragma unroll
    for (int ii = 0; ii < 4; ++ii) {
        int nt = wv * 4 + ii;
        w2b0[ii] = *reinterpret_cast<const bf16x8*>(&W2T[(nt * 16 + l15) * 64 + g * 8]);
        w2b1[ii] = *reinterpret_cast<const bf16x8*>(&W2T[(nt * 16 + l15) * 64 + 32 + g * 8]);
    }

    if (tid < 32 * TILES) eid_s[tid] = order[p0 + tid];
    __syncthreads();

    f32x4 efr[2];
    auto load_ef = [&](int t) {
        int ebase = t * 32;
        #pragma unroll
        for (int r = 0; r < 2; ++r) {
            int q = tid + r * 256;
            int el = q >> 4, qf = q & 15;
            efr[r] = *reinterpret_cast<const f32x4*>(
                edge_feature + (size_t)eid_s[ebase + el] * 64 + qf * 4);
        }
    };
    auto write_ef = [&]() {
        #pragma unroll
        for (int r = 0; r < 2; ++r) {
            int q = tid + r * 256;
            int el = q >> 4, f0 = (q & 15) * 4;
            b16x4 h;
            #pragma unroll
            for (int j = 0; j < 4; ++j) h[j] = (short)f2b(efr[r][j]);
            *reinterpret_cast<b16x4*>(&A1[el * 64 + (f0 ^ ((el & 7) << 3))]) = h;
        }
    };

    load_ef(0);

    for (int t = 0; t < TILES; ++t) {
        write_ef();
        __syncthreads();
        if (t < TILES - 1) load_ef(t + 1);

        // GEMM1: Hs = relu(A1 @ Wfc1)
        {
            const int nt = wv;
            #pragma unroll
            for (int mt = 0; mt < 2; ++mt) {
                f32x4 c4 = {0.f, 0.f, 0.f, 0.f};
                int ra = mt * 16 + l15;
                int sw = (ra & 7) << 3;
                bf16x8 a0 = *reinterpret_cast<const bf16x8*>(&A1[ra * 64 + ((g * 8) ^ sw)]);
                bf16x8 a1 = *reinterpret_cast<const bf16x8*>(&A1[ra * 64 + ((32 + g * 8) ^ sw)]);
                c4 = __builtin_amdgcn_mfma_f32_16x16x32_bf16(a0, w1b0, c4, 0, 0, 0);
                c4 = __builtin_amdgcn_mfma_f32_16x16x32_bf16(a1, w1b1, c4, 0, 0, 0);
                #pragma unroll
                for (int r = 0; r < 4; ++r) {
                    int row = mt * 16 + g * 4 + r;
                    int col = nt * 16 + l15;
                    Hs[row * 64 + (col ^ ((row & 7) << 3))] = f2b(fmaxf(c4[r], 0.f));
                }
            }
        }
        __syncthreads();

        // GEMM2: w_s = Hs @ Wfc2 (stores masked nt<14)
        {
            #pragma unroll
            for (int ii = 0; ii < 4; ++ii) {
                int nt = wv * 4 + ii;
                #pragma unroll
                for (int mt = 0; mt < 2; ++mt) {
                    f32x4 c4 = {0.f, 0.f, 0.f, 0.f};
                    int ra = mt * 16 + l15;
                    int sw = (ra & 7) << 3;
                    bf16x8 a0 = *reinterpret_cast<const bf16x8*>(&Hs[ra * 64 + ((g * 8) ^ sw)]);
                    bf16x8 a1 = *reinterpret_cast<const bf16x8*>(&Hs[ra * 64 + ((32 + g * 8) ^ sw)]);
                    c4 = __builtin_amdgcn_mfma_f32_16x16x32_bf16(a0, w2b0[ii], c4, 0, 0, 0);
                    c4 = __builtin_amdgcn_mfma_f32_16x16x32_bf16(a1, w2b1[ii], c4, 0, 0, 0);
                    if (nt < 14) {
                        #pragma unroll
                        for (int r = 0; r < 4; ++r) {
                            int row = mt * 16 + g * 4 + r;
                            w_s[row * 224 + nt * 16 + l15] = f2b(c4[r]);
                        }
                    }
                }
            }
        }
        __syncthreads();

        // coalesced copy-out: 32x224 u16 = 896 x 16B
        {
            const size_t gbase = (size_t)(p0 + t * 32) * 224;
            for (int idx = tid; idx < 896; idx += 256) {
                *reinterpret_cast<f32x4*>(&w_srt[gbase + idx * 8]) =
                    *reinterpret_cast<const f32x4*>(&w_s[idx * 8]);
            }
        }
    }
}

// ---------------------------------------------------------------------------
// Kernel B: per-NODE messages, v4. Staging masked to nvalid (no padded-chunk
// waste); df f32; w read directly from global; writes agg[n][480] coalesced.
// ---------------------------------------------------------------------------
__global__ __launch_bounds__(256, 7) void node_msg(
    const int* __restrict__ row_start,
    const int* __restrict__ dst_srt,
    const float* __restrict__ sh_srt,
    const unsigned short* __restrict__ w_srt,
    const float* __restrict__ st_vt32,
    float* __restrict__ agg)
{
    __shared__ __align__(16) float df[32 * 160];   // 20480 B (f32)
    __shared__ float aggbuf[480];
    __shared__ float sh_c[32][4];

    // chunked XCD remap (10000 = 8 * 1250)
    const int n   = (blockIdx.x & 7) * 1250 + (blockIdx.x >> 3);
    const int tid = threadIdx.x;
    const int p_start = row_start[n];
    const int p_end   = row_start[n + 1];

    const int tid2 = tid & 127;
    const int half = tid >> 7;
    int region, cb, iv;
    if (tid2 < 48)       { region = 0; cb = tid2 & 15;        iv = tid2 >> 4; }
    else if (tid2 < 64)  { region = 1; cb = tid2 - 48;        iv = 0; }
    else if (tid2 < 88)  { region = 2; cb = (tid2 - 64) & 7;  iv = (tid2 - 64) >> 3; }
    else if (tid2 < 112) { region = 3; cb = (tid2 - 88) & 7;  iv = (tid2 - 88) >> 3; }
    else if (tid2 < 120) { region = 4; cb = tid2 - 112;       iv = 0; }
    else                 { region = 5; cb = 0; iv = 0; }
    int rbase = 0, woff = 0, doff = 0;
    if (region == 0)      { rbase = 96 + iv * 64 + 4 * cb;  woff = 64 + 4 * cb;  doff = 4 * cb; }
    else if (region == 1) { rbase = 4 * cb;                 woff = 4 * cb;       doff = 4 * cb; }
    else if (region == 2) { rbase = 288 + iv * 32 + 4 * cb; woff = 128 + 4 * cb; doff = 64 + iv * 32 + 4 * cb; }
    else if (region == 3) { rbase = 384 + iv * 32 + 4 * cb; woff = 192 + 4 * cb; }
    else if (region == 4) { rbase = 64 + 4 * cb;            woff = 160 + 4 * cb; }
    int i1 = iv + 1; if (i1 == 3) i1 = 0;
    int i2 = 3 - iv - i1;

    f32x4 acc = {0.f, 0.f, 0.f, 0.f};

    for (int pb = p_start; pb < p_end; pb += 32) {
        const int nvalid = min(p_end - pb, 32);
        const int qlimit = nvalid * 40;        // df quads to stage
        __syncthreads();                       // df/sh_c reuse guard

        if (tid < nvalid) {
            *reinterpret_cast<f32x4*>(&sh_c[tid][0]) =
                *reinterpret_cast<const f32x4*>(&sh_srt[(size_t)(pb + tid) * 4]);
        }
        // stage df f32: nvalid*40 quads (active lanes form a prefix per wave)
        #pragma unroll
        for (int r = 0; r < 5; ++r) {
            int idx = tid + r * 256;
            if (idx < qlimit) {
                int el = idx / 40, off = idx - el * 40;
                int d = dst_srt[pb + el];
                gl_lds16(st_vt32 + (size_t)d * 160 + off * 4, &df[idx * 4]);
            }
        }
        __syncthreads();                       // vmcnt drained

        if (region < 5) {
            const int e0l = half * 16;
            #pragma unroll 4
            for (int j2 = 0; j2 < 16; ++j2) {
                int el = e0l + j2;
                if (el >= nvalid) break;       // uniform per half
                const float* dfp = &df[el * 160];
                const unsigned short* we = w_srt + (size_t)(pb + el) * 224;  // GLOBAL
                b16x4 w = *reinterpret_cast<const b16x4*>(we + woff);
                if (region == 0) {
                    f32x4 x = *reinterpret_cast<const f32x4*>(dfp + doff);
                    float sh = sh_c[el][iv];
                    #pragma unroll
                    for (int j = 0; j < 4; ++j)
                        acc[j] += b2f((unsigned short)w[j]) * x[j] * sh;
                } else if (region == 1 || region == 2) {
                    f32x4 x = *reinterpret_cast<const f32x4*>(dfp + doff);
                    #pragma unroll
                    for (int j = 0; j < 4; ++j)
                        acc[j] += b2f((unsigned short)w[j]) * x[j];
                } else if (region == 3) {
                    f32x4 xA = *reinterpret_cast<const f32x4*>(dfp + 64 + i1 * 32 + 4 * cb);
                    f32x4 xB = *reinterpret_cast<const f32x4*>(dfp + 64 + i2 * 32 + 4 * cb);
                    float shA = sh_c[el][i1], shB = sh_c[el][i2];
                    #pragma unroll
                    for (int j = 0; j < 4; ++j)
                        acc[j] += b2f((unsigned short)w[j]) *
                                  (xA[j] * shB - xB[j] * shA) * INV_SQRT2F;
                } else {
                    f32x4 x0 = *reinterpret_cast<const f32x4*>(dfp + 64 + 4 * cb);
                    f32x4 x1 = *reinterpret_cast<const f32x4*>(dfp + 96 + 4 * cb);
                    f32x4 x2 = *reinterpret_cast<const f32x4*>(dfp + 128 + 4 * cb);
                    float s0 = sh_c[el][0], s1 = sh_c[el][1], s2 = sh_c[el][2];
                    #pragma unroll
                    for (int j = 0; j < 4; ++j)
                        acc[j] += b2f((unsigned short)w[j]) *
                                  (x0[j] * s0 + x1[j] * s1 + x2[j] * s2) * INV_SQRT3F;
                }
            }
        }
    }

    // combine halves into aggbuf, write agg coalesced
    __syncthreads();
    if (half == 0 && region < 5) {
        #pragma unroll
        for (int j = 0; j < 4; ++j) aggbuf[rbase + j] = acc[j];
    }
    __syncthreads();
    if (half == 1 && region < 5) {
        #pragma unroll
        for (int j = 0; j < 4; ++j) aggbuf[rbase + j] += acc[j];
    }
    __syncthreads();
    if (tid < 120) {
        *reinterpret_cast<f32x4*>(&agg[(size_t)n * 480 + tid * 4]) =
            *reinterpret_cast<const f32x4*>(&aggbuf[tid * 4]);
    }
}

// ---------------------------------------------------------------------------
// Kernel C: out_gemm. 32 nodes/block, 4 waves, MFMA K=160 fused transforms,
// then silu/sigmoid-gate epilogue, final out[n][160].
// ---------------------------------------------------------------------------
__global__ __launch_bounds__(256) void out_gemm(
    const float* __restrict__ agg,
    const float* __restrict__ nf,
    const unsigned short* __restrict__ WsCombT,
    const unsigned short* __restrict__ WvCombT,
    float* __restrict__ out)
{
    __shared__ float os_l[32][96];       // 12 KB
    __shared__ float ov_l[3][32][32];    // 12 KB

    const int n0  = blockIdx.x * 32;
    const int tid = threadIdx.x;
    const int lane = tid & 63;
    const int wv   = tid >> 6;
    const int l15  = lane & 15;
    const int g    = lane >> 4;

    #pragma unroll
    for (int jj = 0; jj < 6; ++jj) {
        int job = wv * 6 + jj;          // 0..23
        bool isS;
        int mt, nt, ii = 0;
        if (job < 12) { isS = true;  mt = job & 1; nt = job >> 1; }
        else { int j = job - 12; isS = false; ii = j >> 2; mt = (j >> 1) & 1; nt = j & 1; }

        int ra = mt * 16 + l15;
        int n  = min(n0 + ra, N_NODES - 1);
        const float* aggn = agg + (size_t)n * 480;
        const float* nfn  = nf + (size_t)n * 160;
        const unsigned short* WT = isS ? WsCombT : WvCombT;

        f32x4 c4 = {0.f, 0.f, 0.f, 0.f};
        #pragma unroll
        for (int kk = 0; kk < 5; ++kk) {
            int k0 = kk * 32 + g * 8;
            float av[8];
            if (isS) {
                if (k0 < 96) {
                    f32x4 p0 = *reinterpret_cast<const f32x4*>(aggn + k0);
                    f32x4 p1 = *reinterpret_cast<const f32x4*>(aggn + k0 + 4);
                    #pragma unroll
                    for (int j = 0; j < 4; ++j) { av[j] = p0[j] * (1.f/32.f); av[4+j] = p1[j] * (1.f/32.f); }
                } else {
                    f32x4 p0 = *reinterpret_cast<const f32x4*>(nfn + (k0 - 96));
                    f32x4 p1 = *reinterpret_cast<const f32x4*>(nfn + (k0 - 96) + 4);
                    #pragma unroll
                    for (int j = 0; j < 4; ++j) { av[j] = p0[j]; av[4+j] = p1[j]; }
                }
            } else {
                if (k0 < 128) {
                    int base = (k0 < 64) ? (96 + ii * 64 + k0)
                             : (k0 < 96) ? (288 + ii * 32 + (k0 - 64))
                                         : (384 + ii * 32 + (k0 - 96));
                    f32x4 p0 = *reinterpret_cast<const f32x4*>(aggn + base);
                    f32x4 p1 = *reinterpret_cast<const f32x4*>(aggn + base + 4);
                    #pragma unroll
                    for (int j = 0; j < 4; ++j) { av[j] = p0[j] * (1.f/32.f); av[4+j] = p1[j] * (1.f/32.f); }
                } else {
                    #pragma unroll
                    for (int j = 0; j < 8; ++j)
                        av[j] = nfn[64 + (k0 - 128 + j) * 3 + ii];
                }
            }
            bf16x8 a;
            #pragma unroll
            for (int j = 0; j < 8; ++j) a[j] = (short)f2b(av[j]);
            bf16x8 bfr = *reinterpret_cast<const bf16x8*>(
                WT + (size_t)(nt * 16 + l15) * 160 + k0);
            c4 = __builtin_amdgcn_mfma_f32_16x16x32_bf16(a, bfr, c4, 0, 0, 0);
        }
        #pragma unroll
        for (int r = 0; r < 4; ++r) {
            int row = mt * 16 + g * 4 + r;
            int col = nt * 16 + l15;
            if (isS) os_l[row][col] = c4[r];
            else     ov_l[ii][row][col] = c4[r];
        }
    }
    __syncthreads();

    // epilogue: 32 nodes x 160 outputs
    for (int idx = tid; idx < 32 * 160; idx += 256) {
        int r = idx / 160, c = idx - r * 160;
        int n = n0 + r;
        if (n < N_NODES) {
            if (c < 64) {
                float x = os_l[r][c];
                out[(size_t)n * 160 + c] = x / (1.f + expf(-x));      // silu
            } else {
                int t = c - 64;
                int k = t / 3, i = t - 3 * k;
                float gg = os_l[r][64 + k];
                gg = 1.f / (1.f + expf(-gg));                          // sigmoid
                out[(size_t)n * 160 + c] = gg * ov_l[i][r][k];
            }
        }
    }
}

// ---------------------------------------------------------------------------
// Fallback path (only if ws can't hold w_srt): fused kernel + out.
// ---------------------------------------------------------------------------
__global__ __launch_bounds__(256, 3) void edge_conv_fused(
    const unsigned short* __restrict__ W1T,
    const unsigned short* __restrict__ W2T,
    const int* __restrict__ order,
    const int* __restrict__ src_srt,
    const int* __restrict__ dst_srt,
    const float* __restrict__ sh_srt,
    const float* __restrict__ edge_feature,
    const unsigned short* __restrict__ st_vt16,
    float* __restrict__ agg)
{
    __shared__ __align__(16) unsigned short A1[32 * 64];
    __shared__ __align__(16) unsigned short Hs[32 * 64];
    __shared__ __align__(16) unsigned short w_s[32 * 224];
    __shared__ __align__(16) unsigned short df[2][32 * 160];
    __shared__ int   eid_s[32 * TILES];
    __shared__ int   src_s[32 * TILES];
    __shared__ int   dst_s[32 * TILES];
    __shared__ float sh_s[32 * TILES][4];

    const int tid  = threadIdx.x;
    const int lane = tid & 63;
    const int wv   = tid >> 6;
    const int l15  = lane & 15;
    const int g    = lane >> 4;
    const int p0   = blockIdx.x * (32 * TILES);

    bf16x8 w1b0 = *reinterpret_cast<const bf16x8*>(&W1T[(wv * 16 + l15) * 64 + g * 8]);
    bf16x8 w1b1 = *reinterpret_cast<const bf16x8*>(&W1T[(wv * 16 + l15) * 64 + 32 + g * 8]);
    bf16x8 w2b0[4], w2b1[4];
    #pragma unroll
    for (int ii = 0; ii < 4; ++ii) {
        int nt = wv * 4 + ii;
        w2b0[ii] = *reinterpret_cast<const bf16x8*>(&W2T[(nt * 16 + l15) * 64 + g * 8]);
        w2b1[ii] = *reinterpret_cast<const bf16x8*>(&W2T[(nt * 16 + l15) * 64 + 32 + g * 8]);
    }

    for (int b = tid; b < 32 * TILES; b += 256) {
        int p = p0 + b;
        eid_s[b] = order[p];
        src_s[b] = src_srt[p];
        dst_s[b] = dst_srt[p];
        *reinterpret_cast<f32x4*>(&sh_s[b][0]) =
            *reinterpret_cast<const f32x4*>(&sh_srt[(size_t)p * 4]);
    }
    __syncthreads();

    const int tid2 = tid & 127;
    int region, cb, iv;
    if (tid2 < 48)       { region = 0; cb = tid2 & 15;        iv = tid2 >> 4; }
    else if (tid2 < 64)  { region = 1; cb = tid2 - 48;        iv = 0; }
    else if (tid2 < 88)  { region = 2; cb = (tid2 - 64) & 7;  iv = (tid2 - 64) >> 3; }
    else if (tid2 < 112) { region = 3; cb = (tid2 - 88) & 7;  iv = (tid2 - 88) >> 3; }
    else if (tid2 < 120) { region = 4; cb = tid2 - 112;       iv = 0; }
    else                 { region = 5; cb = 0; iv = 0; }
    int rbase = 0, woff = 0, doff = 0;
    if (region == 0)      { rbase = 96 + iv * 64 + 4 * cb;  woff = 64 + 4 * cb;  doff = 4 * cb; }
    else if (region == 1) { rbase = 4 * cb;                 woff = 4 * cb;       doff = 4 * cb; }
    else if (region == 2) { rbase = 288 + iv * 32 + 4 * cb; woff = 128 + 4 * cb; doff = 64 + iv * 32 + 4 * cb; }
    else if (region == 3) { rbase = 384 + iv * 32 + 4 * cb; woff = 192 + 4 * cb; }
    else if (region == 4) { rbase = 64 + 4 * cb;            woff = 160 + 4 * cb; }
    int i1 = iv + 1; if (i1 == 3) i1 = 0;
    int i2 = 3 - iv - i1;

    f32x4 acc = {0.f, 0.f, 0.f, 0.f};
    int cur = src_s[(tid >> 7) * 16];

    f32x4 efr[2];
    auto load_ef = [&](int t) {
        int ebase = t * 32;
        #pragma unroll
        for (int r = 0; r < 2; ++r) {
            int q = tid + r * 256;
            int el = q >> 4, qf = q & 15;
            efr[r] = *reinterpret_cast<const f32x4*>(
                edge_feature + (size_t)eid_s[ebase + el] * 64 + qf * 4);
        }
    };
    auto write_ef = [&]() {
        #pragma unroll
        for (int r = 0; r < 2; ++r) {
            int q = tid + r * 256;
            int el = q >> 4, f0 = (q & 15) * 4;
            b16x4 h;
            #pragma unroll
            for (int j = 0; j < 4; ++j) h[j] = (short)f2b(efr[r][j]);
            *reinterpret_cast<b16x4*>(&A1[el * 64 + (f0 ^ ((el & 7) << 3))]) = h;
        }
    };
    auto issue_df = [&](int t, int b) {
        int ebase = t * 32;
        #pragma unroll
        for (int r = 0; r < 3; ++r) {
            int idx = tid + r * 256;
            if (idx < 640) {
                int el = idx / 20, off = idx - el * 20;
                gl_lds16(st_vt16 + (size_t)dst_s[ebase + el] * 160 + off * 8,
                         &df[b][idx * 8]);
            }
        }
    };

    issue_df(0, 0);
    load_ef(0);

    for (int t = 0; t < TILES; ++t) {
        const int b = t & 1;
        write_ef();
        __syncthreads();
        if (t < TILES - 1) {
            issue_df(t + 1, b ^ 1);
            load_ef(t + 1);
        }
        {
            const int nt = wv;
            #pragma unroll
            for (int mt = 0; mt < 2; ++mt) {
                f32x4 c4 = {0.f, 0.f, 0.f, 0.f};
                int ra = mt * 16 + l15;
                int sw = (ra & 7) << 3;
                bf16x8 a0 = *reinterpret_cast<const bf16x8*>(&A1[ra * 64 + ((g * 8) ^ sw)]);
                bf16x8 a1 = *reinterpret_cast<const bf16x8*>(&A1[ra * 64 + ((32 + g * 8) ^ sw)]);
                c4 = __builtin_amdgcn_mfma_f32_16x16x32_bf16(a0, w1b0, c4, 0, 0, 0);
                c4 = __builtin_amdgcn_mfma_f32_16x16x32_bf16(a1, w1b1, c4, 0, 0, 0);
                #pragma unroll
                for (int r = 0; r < 4; ++r) {
                    int row = mt * 16 + g * 4 + r;
                    int col = nt * 16 + l15;
                    Hs[row * 64 + (col ^ ((row & 7) << 3))] = f2b(fmaxf(c4[r], 0.f));
                }
            }
        }
        __syncthreads();
        {
            #pragma unroll
            for (int ii = 0; ii < 4; ++ii) {
                int nt = wv * 4 + ii;
                #pragma unroll
                for (int mt = 0; mt < 2; ++mt) {
                    f32x4 c4 = {0.f, 0.f, 0.f, 0.f};
                    int ra = mt * 16 + l15;
                    int sw = (ra & 7) << 3;
                    bf16x8 a0 = *reinterpret_cast<const bf16x8*>(&Hs[ra * 64 + ((g * 8) ^ sw)]);
                    bf16x8 a1 = *reinterpret_cast<const bf16x8*>(&Hs[ra * 64 + ((32 + g * 8) ^ sw)]);
                    c4 = __builtin_amdgcn_mfma_f32_16x16x32_bf16(a0, w2b0[ii], c4, 0, 0, 0);
                    c4 = __builtin_amdgcn_mfma_f32_16x16x32_bf16(a1, w2b1[ii], c4, 0, 0, 0);
                    if (nt < 14) {
                        #pragma unroll
                        for (int r = 0; r < 4; ++r) {
                            int row = mt * 16 + g * 4 + r;
                            w_s[row * 224 + nt * 16 + l15] = f2b(c4[r]);
                        }
                    }
                }
            }
        }
        __syncthreads();
        if (region < 5) {
            const int e0l = (tid >> 7) * 16;
            #pragma unroll 4
            for (int j2 = 0; j2 < 16; ++j2) {
                int el = e0l + j2;
                int eg = t * 32 + el;
                int s = src_s[eg];
                if (s != cur) {
                    #pragma unroll
                    for (int j = 0; j < 4; ++j)
                        atomicAdd(&agg[(size_t)cur * 480 + rbase + j], acc[j]);
                    acc = (f32x4){0.f, 0.f, 0.f, 0.f};
                    cur = s;
                }
                const unsigned short* dfp = &df[b][el * 160];
                const unsigned short* we  = &w_s[el * 224];
                b16x4 w = *reinterpret_cast<const b16x4*>(we + woff);
                if (region == 0) {
                    b16x4 x = *reinterpret_cast<const b16x4*>(dfp + doff);
                    float sh = sh_s[eg][iv];
                    #pragma unroll
                    for (int j = 0; j < 4; ++j)
                        acc[j] += b2f((unsigned short)w[j]) * b2f((unsigned short)x[j]) * sh;
                } else if (region == 1 || region == 2) {
                    b16x4 x = *reinterpret_cast<const b16x4*>(dfp + doff);
                    #pragma unroll
                    for (int j = 0; j < 4; ++j)
                        acc[j] += b2f((unsigned short)w[j]) * b2f((unsigned short)x[j]);
                } else if (region == 3) {
                    b16x4 xA = *reinterpret_cast<const b16x4*>(dfp + 64 + i1 * 32 + 4 * cb);
                    b16x4 xB = *reinterpret_cast<const b16x4*>(dfp + 64 + i2 * 32 + 4 * cb);
                    float shA = sh_s[eg][i1], shB = sh_s[eg][i2];
                    #pragma unroll
                    for (int j = 0; j < 4; ++j)
                        acc[j] += b2f((unsigned short)w[j]) *
                                  (b2f((unsigned short)xA[j]) * shB -
                                   b2f((unsigned short)xB[j]) * shA) * INV_SQRT2F;
                } else {
                    b16x4 x0 = *reinterpret_cast<const b16x4*>(dfp + 64 + 4 * cb);
                    b16x4 x1 = *reinterpret_cast<const b16x4*>(dfp + 96 + 4 * cb);
                    b16x4 x2 = *reinterpret_cast<const b16x4*>(dfp + 128 + 4 * cb);
                    float s0 = sh_s[eg][0], s1 = sh_s[eg][1], s2 = sh_s[eg][2];
                    #pragma unroll
                    for (int j = 0; j < 4; ++j)
                        acc[j] += b2f((unsigned short)w[j]) *
                                  (b2f((unsigned short)x0[j]) * s0 +
                                   b2f((unsigned short)x1[j]) * s1 +
                                   b2f((unsigned short)x2[j]) * s2) * INV_SQRT3F;
                }
            }
        }
    }
    if (region < 5) {
        #pragma unroll
        for (int j = 0; j < 4; ++j)
            atomicAdd(&agg[(size_t)cur * 480 + rbase + j], acc[j]);
    }
}

__global__ __launch_bounds__(128) void out_kernel(
    const float* __restrict__ agg,
    const float* __restrict__ nf,
    const float* __restrict__ Wskip0,
    const float* __restrict__ Wskip1,
    const float* __restrict__ Wout_s,
    const float* __restrict__ Wout_v,
    float* __restrict__ out)
{
    __shared__ float aggl[480];
    __shared__ float os_s[96];
    const int n = blockIdx.x;
    const int tid = threadIdx.x;
    const float* nfn = nf + (size_t)n * 160;

    for (int idx = tid; idx < 480; idx += 128)
        aggl[idx] = agg[(size_t)n * 480 + idx] * (1.f / 32.f);
    __syncthreads();

    if (tid < 96) {
        float acc = 0.f;
        #pragma unroll 8
        for (int k = 0; k < 64; ++k) acc += nfn[k] * Wskip0[k * 96 + tid];
        for (int r = 0; r < 96; ++r) acc += aggl[r] * Wout_s[r * 96 + tid];
        os_s[tid] = acc;
    }
    __syncthreads();

    if (tid < 64) {
        float x = os_s[tid];
        out[(size_t)n * 160 + tid] = x / (1.f + expf(-x));
    }
    if (tid < 96) {
        int t = tid;
        int k = t / 3, i = t - 3 * k;
        float acc = 0.f;
        #pragma unroll 8
        for (int m = 0; m < 32; ++m) acc += nfn[64 + m * 3 + i] * Wskip1[m * 32 + k];
        #pragma unroll 8
        for (int m = 0; m < 64; ++m) acc += aggl[96 + i * 64 + m] * Wout_v[m * 32 + k];
        #pragma unroll 8
        for (int m = 0; m < 32; ++m) acc += aggl[288 + i * 32 + m] * Wout_v[(64 + m) * 32 + k];
        #pragma unroll 8
        for (int m = 0; m < 32; ++m) acc += aggl[384 + i * 32 + m] * Wout_v[(96 + m) * 32 + k];
        float g = os_s[64 + k];
        g = 1.f / (1.f + expf(-g));
        out[(size_t)n * 160 + 64 + t] = g * acc;
    }
}

// ---------------------------------------------------------------------------
extern "C" void kernel_launch(void* const* d_in, const int* in_sizes, int n_in,
                              void* d_out, int out_size, void* d_ws, size_t ws_size,
                              hipStream_t stream)
{
    const float* nf     = (const float*)d_in[0];
    const float* ea     = (const float*)d_in[1];
    const float* ef     = (const float*)d_in[2];
    const float* Wskip0 = (const float*)d_in[3];
    const float* Wskip1 = (const float*)d_in[4];
    const float* Wnl0   = (const float*)d_in[5];
    const float* Wnl1   = (const float*)d_in[6];
    const float* Wfc1   = (const float*)d_in[7];
    const float* Wfc2   = (const float*)d_in[8];
    const float* Wout_s = (const float*)d_in[9];
    const float* Wout_v = (const float*)d_in[10];
    const int*   eidx   = (const int*)d_in[11];
    float* out = (float*)d_out;

    // workspace layout (16B-aligned sections)
    int*   cnt       = (int*)d_ws;                        // 10000
    int*   fill      = cnt + 10000;                       // 10000
    int*   row_start = fill + 10000;                      // 10004
    int*   order     = row_start + 10004;                 // 320000
    int*   src_srt   = order + 320000;                    // 320000
    int*   dst_srt   = src_srt + 320000;                  // 320000
    float* sh_srt    = (float*)(dst_srt + 320000);        // 1,280,000
    float* agg       = sh_srt + 1280000;                  // 4,800,000
    float* st_vt32   = agg + 4800000;                     // 1,600,000
    unsigned short* st_vt16 = (unsigned short*)(st_vt32 + 1600000); // 1,600,000
    unsigned short* W1T     = st_vt16 + 1600000;          // 4,096
    unsigned short* W2T     = W1T + 4096;                 // 16,384
    unsigned short* WsCombT = W2T + 16384;                // 15,360
    unsigned short* WvCombT = WsCombT + 15360;            // 5,120 (+pad 32)
    unsigned short* w_srt   = WvCombT + 5152;             // (N_EDGES+32)*224

    const size_t need_split =
        (size_t)((const char*)(w_srt + (size_t)(N_EDGES + 32) * 224) - (const char*)d_ws);
    const bool use_split = (ws_size >= need_split);

    hipMemsetAsync(cnt, 0, 20000 * sizeof(int), stream);   // cnt+fill

    prep_kernel<<<7652, 256, 0, stream>>>(
        nf, Wnl0, Wnl1, Wfc1, Wfc2, Wout_s, Wout_v, Wskip0, Wskip1,
        eidx, st_vt32, st_vt16, W1T, W2T, WsCombT, WvCombT, cnt);

    scan_kernel<<<1, 1024, 0, stream>>>(cnt, row_start);
    scatter_kernel<<<(N_EDGES + 255) / 256, 256, 0, stream>>>(
        eidx, ea, row_start, fill, order, src_srt, dst_srt, sh_srt);

    if (use_split) {
        edge_mlp<<<NBLK, 256, 0, stream>>>(W1T, W2T, order, ef, w_srt);
        node_msg<<<N_NODES, 256, 0, stream>>>(
            row_start, dst_srt, sh_srt, w_srt, st_vt32, agg);
        out_gemm<<<(N_NODES + 31) / 32, 256, 0, stream>>>(
            agg, nf, WsCombT, WvCombT, out);
    } else {
        hipMemsetAsync(agg, 0, (size_t)N_NODES * 480 * sizeof(float), stream);
        edge_conv_fused<<<NBLK, 256, 0, stream>>>(
            W1T, W2T, order, src_srt, dst_srt, sh_srt, ef, st_vt16, agg);
        out_kernel<<<N_NODES, 128, 0, stream>>>(
            agg, nf, Wskip0, Wskip1, Wout_s, Wout_v, out);
    }
}